// Round 9
// baseline (461.591 us; speedup 1.0000x reference)
//
#include <hip/hip_runtime.h>
#include <math.h>

// Attention_5471788335537 on gfx950: b=8, dim=256, 32x32, heads=8, dhead=64.
// Round 18: single-kernel fusion of prep->qkv->attn->out with a SOFTWARE
// generation barrier (plain launch — capture-safe; r12's crash used the
// cooperative API, which is the forbidden part). Co-residency by construction:
// 512 blocks x 256 thr, 64KB LDS union -> exactly 2 blocks/CU x 256 CU = 512;
// __launch_bounds__(256,2) caps VGPR at 128 (phase maxima 88-92). Barrier:
// __device__ counter, generation scheme (old/512+1)*512 — no reset needed
// across graph replays; device-scope fence + agent-scope atomics (G16);
// bounded spin converts any deadlock into wrong-answer, not container death.
// Rationale: kernel-time sum ~90-95us (qkv 57.5 measured; attn ~14 by LDS
// arithmetic; out ~6; prep ~12) vs wall 168 -> ~70us is dispatch boundaries.
// Phase bodies transplanted from r17 (qkv r14-dbuf verbatim; attn single-buf
// round-6 form to fit 64KB union; out dbuf; prep r17 coalesced map).
// Ledger: r10 96KB qkv LDS -> 1 wave/SIMD; r11 B-direct -> uncoalesced;
// r12 cooperative -> crash; r15 vmcnt(N)+sched_barrier -> -8us; qkv noise
// band +-5us; absmax sits AT 0.015625 — numerics must not change.
#define BATCH 8
#define DIM   256
#define NPIX  1024
#define DHEAD 64
#define INNER 512
#define KVCH  1024
#define PPIX  1156   // 34*34 padded pixels
#define NBLK  512

typedef _Float16 half8 __attribute__((ext_vector_type(8)));
typedef _Float16 half4 __attribute__((ext_vector_type(4)));
typedef float    f32x4 __attribute__((ext_vector_type(4)));
typedef float    f32x16 __attribute__((ext_vector_type(16)));
#define MFMA16(a, b, c) __builtin_amdgcn_mfma_f32_16x16x32_f16(a, b, c, 0, 0, 0)
#define MFMA32(a, b, c) __builtin_amdgcn_mfma_f32_32x32x16_f16(a, b, c, 0, 0, 0)

__device__ unsigned int g_ctr;   // zero at load; stays a multiple of NBLK

static __device__ __forceinline__ void gsync() {
    __threadfence();                       // flush writes device-scope
    __syncthreads();
    if (threadIdx.x == 0) {
        unsigned old = __hip_atomic_fetch_add(&g_ctr, 1u, __ATOMIC_ACQ_REL,
                                              __HIP_MEMORY_SCOPE_AGENT);
        unsigned tgt = (old / NBLK + 1u) * NBLK;
        unsigned spins = 0;
        while (__hip_atomic_load(&g_ctr, __ATOMIC_ACQUIRE,
                                 __HIP_MEMORY_SCOPE_AGENT) < tgt) {
            if (++spins > 4000000u) break;  // safety valve: never deadlock
        }
    }
    __syncthreads();
}

static __device__ __forceinline__ float gelu_f(float v) {
    return 0.5f * v * (1.0f + erff(v * 0.70710678118654752440f));
}

static __device__ __forceinline__ void gload16(const _Float16* g, _Float16* l) {
    __builtin_amdgcn_global_load_lds(
        (const __attribute__((address_space(1))) unsigned int*)g,
        (__attribute__((address_space(3))) unsigned int*)l, 16, 0, 0);
}

// 64 KB LDS union -> 2 blocks/CU (128 KB of 160).
union SMem {
    float ts[64][65];                                                   // 16.6 KB
    float slab[2304];                                                   // 9.2 KB
    struct { _Float16 A0[8192], A1[8192], B0[8192], B1[8192]; } qk;     // 64 KB
    struct { _Float16 Ks[8192], Vs[8192], Pb[16384]; } at;              // 64 KB
    struct { _Float16 A0[8192], A1[8192], B0[4096], B1[4096]; } op;     // 48 KB
};

// ---------------------------------------------------------------------------
// prep unit (r17 map, 3616 units): [0,512) transpose x -> padded xtp interior;
// [512,1024) Wq->f16; [1024,2048) Wkv reorder via LDS slab (coalesced both
// sides, stride-9 LDS reads conflict-free); [2048,2560) Wout->f16;
// [2560,3616) zero xtp halo. Trailing syncthreads: LDS reuse across the
// grid-stride loop.
// ---------------------------------------------------------------------------
static __device__ void prep_unit(
    int u, int tid, SMem* sm,
    const float* __restrict__ Wq, const float* __restrict__ Wkv,
    const float* __restrict__ Wout, const float* __restrict__ x,
    _Float16* __restrict__ Aq, _Float16* __restrict__ Akv,
    _Float16* __restrict__ Aout, _Float16* __restrict__ xtp)
{
    if (u < 512) {
        float (*ts)[65] = sm->ts;
        const int pt = (u & 15) * 64, ic0 = ((u >> 4) & 3) * 64, b = u >> 6;
        const float* xb = x + (((size_t)(b * DIM + ic0)) << 10) + pt;
#pragma unroll
        for (int e = tid; e < 4096; e += 256) {
            int i = e >> 6, p = e & 63;
            ts[i][p] = xb[((size_t)i << 10) + p];
        }
        __syncthreads();
#pragma unroll
        for (int e = tid; e < 512; e += 256) {
            int p = e >> 3, ig = e & 7;
            int gp = pt + p, y = gp >> 5, xc = gp & 31;
            half8 v;
#pragma unroll
            for (int uu = 0; uu < 8; ++uu) v[uu] = (_Float16)ts[ig * 8 + uu][p];
            *(half8*)&xtp[((size_t)b * PPIX + (y + 1) * 34 + xc + 1) * 256 + ic0 + ig * 8] = v;
        }
    } else if (u < 1024) {
        const int e = (u - 512) * 256 + tid;
        Aq[e] = (_Float16)Wq[e];
    } else if (u < 2048) {
        float* slab = sm->slab;
        const int oc = u - 1024;
        const float* src = Wkv + (size_t)oc * 2304;
#pragma unroll
        for (int j = tid; j < 2304; j += 256) slab[j] = src[j];
        __syncthreads();
        _Float16* dst = Akv + (size_t)oc * 2304;
#pragma unroll
        for (int j = tid; j < 2304; j += 256) {
            const int ic = j & 255, s = j >> 8;    // j = s*256 + ic
            dst[j] = (_Float16)slab[ic * 9 + s];
        }
    } else if (u < 2560) {
        const int e = (u - 2048) * 256 + tid;
        Aout[e] = (_Float16)Wout[e];
    } else {
        const int he = (u - 2560) * 256 + tid;   // [0,270336) exact
        int b = he / 33792;                      // 132*256 per batch
        int r = he - b * 33792;
        int hp = r >> 8, ic = r & 255;
        int row, col;
        if (hp < 34)      { row = 0;  col = hp; }
        else if (hp < 68) { row = 33; col = hp - 34; }
        else { int k2 = hp - 68; row = 1 + (k2 >> 1); col = (k2 & 1) * 33; }
        xtp[((size_t)b * PPIX + row * 34 + col) * 256 + ic] = (_Float16)0.f;
    }
    __syncthreads();   // LDS safe for next grid-stride unit / next phase
}

// ---------------------------------------------------------------------------
// qkv unit — r14 schedule verbatim (57.3us best): 32x32x16 MFMA, tile
// 128x128, waves 2x2, dbuf As0/As1/Bs0/Bs1, pairwise kt unroll,
// STAGE(next)->COMPUTE(cur)->__syncthreads. QBLK: A=Aq (4 kts), q*0.125.
// !QBLK: A=Akv (36 kts); m<512 -> K headwise, m>=512 -> V channel-major.
// ---------------------------------------------------------------------------
static __device__ void qkv_unit(
    bool QBLK, int mtl, int nt, int b, int tid,
    _Float16* As0, _Float16* As1, _Float16* Bs0, _Float16* Bs1,
    const _Float16* __restrict__ Akv, const _Float16* __restrict__ Aq,
    const _Float16* __restrict__ xtp, _Float16* __restrict__ qt,
    _Float16* __restrict__ ktp, _Float16* __restrict__ vb)
{
    const int w = tid >> 6, lane = tid & 63;
    const int l31 = lane & 31, kh = lane >> 5;
    const int m0 = mtl * 128, p0 = nt * 128;
    const int wm = (w >> 1) * 64, wn = (w & 1) * 64;

    const int srow = lane >> 3;
    const int scol = ((lane & 7) ^ srow) * 8;

    const _Float16* abase = QBLK ? Aq : Akv;
    const int astride = QBLK ? 256 : 2304;
    const int ktend = QBLK ? 4 : 36;

    const _Float16* agp[4];
    const _Float16* bgp[4];
#pragma unroll
    for (int c = 0; c < 4; ++c) {
        int row = (w * 4 + c) * 8 + srow;
        agp[c] = abase + (size_t)(m0 + row) * astride + scol;
        int p = p0 + row, py = p >> 5, px = p & 31;
        bgp[c] = xtp + ((size_t)b * PPIX + (py + 1) * 34 + px + 1) * 256 + scol;
    }

    f32x16 acc[2][2];
#pragma unroll
    for (int mf = 0; mf < 2; ++mf)
#pragma unroll
        for (int nf = 0; nf < 2; ++nf)
#pragma unroll
            for (int r = 0; r < 16; ++r) acc[mf][nf][r] = 0.f;

    auto STAGE = [&](int kt, _Float16* Asb, _Float16* Bsb) {
        const int s = QBLK ? 4 : (kt >> 2);
        const int doff = (s / 3 - 1) * 34 + (s - (s / 3) * 3) - 1;   // dy*34+dx
        const int boff = doff * 256 + (kt & 3) * 64;                 // wave-uniform
#pragma unroll
        for (int c = 0; c < 4; ++c)
            gload16(agp[c] + kt * 64, &Asb[(w * 4 + c) * 512]);
#pragma unroll
        for (int c = 0; c < 4; ++c)
            gload16(bgp[c] + boff, &Bsb[(w * 4 + c) * 512]);
    };

    auto COMPUTE = [&](const _Float16* Asb, const _Float16* Bsb) {
#pragma unroll
        for (int kc = 0; kc < 4; ++kc) {
            const int cx = ((((kc << 1) | kh) ^ (l31 & 7)) << 3);
            half8 af[2], bf[2];
#pragma unroll
            for (int mf = 0; mf < 2; ++mf)
                af[mf] = *(const half8*)&Asb[(wm + mf * 32 + l31) * 64 + cx];
#pragma unroll
            for (int nf = 0; nf < 2; ++nf)
                bf[nf] = *(const half8*)&Bsb[(wn + nf * 32 + l31) * 64 + cx];
#pragma unroll
            for (int mf = 0; mf < 2; ++mf)
#pragma unroll
                for (int nf = 0; nf < 2; ++nf)
                    acc[mf][nf] = MFMA32(af[mf], bf[nf], acc[mf][nf]);
        }
    };

    STAGE(0, As0, Bs0);
    __syncthreads();

    for (int kt2 = 0; kt2 < ktend; kt2 += 2) {
        STAGE(kt2 + 1, As1, Bs1);
        COMPUTE(As0, Bs0);
        __syncthreads();
        if (kt2 + 2 < ktend) STAGE(kt2 + 2, As0, Bs0);
        COMPUTE(As1, Bs1);
        __syncthreads();
    }

#pragma unroll
    for (int mf = 0; mf < 2; ++mf) {
        const int mbase = m0 + wm + mf * 32;
        if (!QBLK && mbase >= 512) {
            // V: f16 channel-major [(b*512 + m-512)<<10 + pix]
#pragma unroll
            for (int nf = 0; nf < 2; ++nf) {
                const int pix = p0 + wn + nf * 32 + l31;
#pragma unroll
                for (int reg = 0; reg < 16; ++reg) {
                    const int mv = mbase - 512 + (reg & 3) + 8 * (reg >> 2) + 4 * kh;
                    vb[(((size_t)(b * 512 + mv)) << 10) + pix] =
                        (_Float16)acc[mf][nf][reg];
                }
            }
        } else {
            // headwise: [(b*8+h)<<10 + pix][64], d contiguous in groups of 4
            const int h = mbase >> 6;
            const int dbase = (mbase & 63) + kh * 4;
            _Float16* dst = QBLK ? qt : ktp;
#pragma unroll
            for (int nf = 0; nf < 2; ++nf) {
                const int pix = p0 + wn + nf * 32 + l31;
#pragma unroll
                for (int g = 0; g < 4; ++g) {
                    half4 v4;
#pragma unroll
                    for (int r = 0; r < 4; ++r) {
                        float vv = acc[mf][nf][g * 4 + r];
                        if (QBLK) vv *= 0.125f;
                        v4[r] = (_Float16)vv;
                    }
                    *(half4*)&dst[((((size_t)(b * 8 + h)) << 10) + pix) * 64 + dbase + g * 8] = v4;
                }
            }
        }
    }
    __syncthreads();   // LDS safe for a second unit on this block
}

// ---------------------------------------------------------------------------
// attn unit (round-6 single-buffered form — fits the 64KB union): native exp,
// ones-MFMA row sums, S^T layout, xor-swizzled staging, wave-private P,
// fused gelu + gout repack.
// ---------------------------------------------------------------------------
static __device__ void attn_unit(
    int qtile, int bh, int tid,
    _Float16* Ks, _Float16* Vs, _Float16* Pb,
    const _Float16* __restrict__ qt, const _Float16* __restrict__ ktp,
    const _Float16* __restrict__ vbb, _Float16* __restrict__ gout)
{
    const int b = bh >> 3, h = bh & 7;
    const int p0 = qtile * 128;
    const int w = tid >> 6, lane = tid & 63;
    const int quad = lane >> 4, l15 = lane & 15;
    const f32x4 Z4 = {0.f, 0.f, 0.f, 0.f};

    half8 ones;
#pragma unroll
    for (int u = 0; u < 8; ++u) ones[u] = (_Float16)1.0f;

    half8 qf[2][2];
    {
        const _Float16* qrow =
            qt + ((((size_t)(bh)) << 10) + p0 + w * 32 + l15) * 64;
#pragma unroll
        for (int iff = 0; iff < 2; ++iff)
#pragma unroll
            for (int ks = 0; ks < 2; ++ks)
                qf[iff][ks] = *(const half8*)(qrow + iff * 16 * 64 + ks * 32 + quad * 8);
    }

    const _Float16* kbase = ktp + ((size_t)bh << 16);
    const _Float16* vbase = vbb + (((size_t)(b * 512 + h * 64)) << 10);

    f32x4 oacc[4][2];
#pragma unroll
    for (int mf = 0; mf < 4; ++mf)
#pragma unroll
        for (int iff = 0; iff < 2; ++iff) oacc[mf][iff] = Z4;
    f32x4 racc[2] = {Z4, Z4};

    const int kchunk = (lane & 7) ^ (lane >> 3);
    for (int kt = 0; kt < 8; ++kt) {
        const int pk = kt * 128;
        __syncthreads();
        const _Float16* kg = kbase + (size_t)pk * 64;
#pragma unroll
        for (int i = 0; i < 4; ++i) {
            const int t = i * 4 + w;
            gload16(kg + (t * 8 + (lane >> 3)) * 64 + kchunk * 8, &Ks[t * 512]);
        }
#pragma unroll
        for (int i = 0; i < 4; ++i) {
            const int t = i * 4 + w;
            const int vd = t * 4 + (lane >> 4);
            gload16(vbase + ((size_t)vd << 10) + pk + (((lane & 15) ^ (vd & 15)) << 3),
                    &Vs[t * 512]);
        }
        __syncthreads();

#pragma unroll
        for (int g = 0; g < 2; ++g) {
            f32x4 s[4][2];
#pragma unroll
            for (int jf2 = 0; jf2 < 4; ++jf2) {
                const int jr = (g * 4 + jf2) * 16 + l15;
                const half8 ka0 = *(const half8*)&Ks[jr * 64 + ((quad ^ (l15 & 7)) << 3)];
                const half8 ka1 = *(const half8*)&Ks[jr * 64 + (((4 + quad) ^ (l15 & 7)) << 3)];
#pragma unroll
                for (int iff = 0; iff < 2; ++iff) {
                    s[jf2][iff] = MFMA16(ka0, qf[iff][0], Z4);
                    s[jf2][iff] = MFMA16(ka1, qf[iff][1], s[jf2][iff]);
                }
            }
#pragma unroll
            for (int jf2 = 0; jf2 < 4; ++jf2) {
#pragma unroll
                for (int iff = 0; iff < 2; ++iff) {
                    half4 pv4;
#pragma unroll
                    for (int r = 0; r < 4; ++r)
                        pv4[r] = (_Float16)__expf(s[jf2][iff][r] - 8.0f);
                    const int i = w * 32 + iff * 16 + l15;
                    const int c = ((g * 4 + jf2) << 1) + (quad >> 1);
                    *(half4*)&Pb[i * 128 + ((c ^ l15) << 3) + ((quad & 1) << 2)] = pv4;
                }
            }
        }
#pragma unroll
        for (int kc = 0; kc < 4; ++kc) {
            half8 bv[2];
#pragma unroll
            for (int iff = 0; iff < 2; ++iff) {
                const int i = w * 32 + iff * 16 + l15;
                bv[iff] = *(const half8*)&Pb[i * 128 + (((kc * 4 + quad) ^ l15) << 3)];
                racc[iff] = MFMA16(ones, bv[iff], racc[iff]);
            }
#pragma unroll
            for (int mf = 0; mf < 4; ++mf) {
                const int vr = mf * 16 + l15;
                const half8 va = *(const half8*)&Vs[vr * 128 + (((kc * 4 + quad) ^ l15) << 3)];
#pragma unroll
                for (int iff = 0; iff < 2; ++iff)
                    oacc[mf][iff] = MFMA16(va, bv[iff], oacc[mf][iff]);
            }
        }
    }

    float rinv[2];
#pragma unroll
    for (int iff = 0; iff < 2; ++iff) rinv[iff] = 1.f / racc[iff][0];

    __syncthreads();
    _Float16* scr = Pb;  // [128 rows][72 halves]
#pragma unroll
    for (int mf = 0; mf < 4; ++mf) {
#pragma unroll
        for (int iff = 0; iff < 2; ++iff) {
            half4 o4;
#pragma unroll
            for (int r = 0; r < 4; ++r)
                o4[r] = (_Float16)gelu_f(oacc[mf][iff][r] * rinv[iff]);
            const int i = w * 32 + iff * 16 + l15;
            *(half4*)&scr[i * 72 + mf * 16 + quad * 4] = o4;
        }
    }
    __syncthreads();
    _Float16* go = gout + ((size_t)(b * NPIX + p0)) * INNER + h * 64;
#pragma unroll
    for (int it = 0; it < 4; ++it) {
        const int e = tid + it * 256;
        const int p = e >> 3, dg = e & 7;
        *(half8*)(go + (size_t)p * INNER + dg * 8) = *(const half8*)&scr[p * 72 + dg * 8];
    }
    __syncthreads();
}

// ---------------------------------------------------------------------------
// out-projection unit (r17 dbuf form): 16x16x32, tile 128M x 64N, K=512.
// ---------------------------------------------------------------------------
static __device__ void out_unit(
    int nt, int mt, int b, int tid,
    _Float16* As0, _Float16* As1, _Float16* Bs0, _Float16* Bs1,
    const _Float16* __restrict__ A, const _Float16* __restrict__ act,
    float* __restrict__ Cout, const float* __restrict__ bias)
{
    const int K = 512, KROW = 512, M = DIM;
    const int w = tid >> 6, lane = tid & 63;
    const int quad = lane >> 4, l15 = lane & 15;
    const int m0 = mt * 128, p0 = nt * 64;
    const int wm = w * 32;
    const f32x4 Z4 = {0.f, 0.f, 0.f, 0.f};

    const int srow = lane >> 3;
    const int scol = ((lane & 7) ^ srow) * 8;

    const _Float16* agp[4];
#pragma unroll
    for (int c = 0; c < 4; ++c) {
        int row = (w * 4 + c) * 8 + srow;
        agp[c] = A + (size_t)(m0 + row) * K + scol;
    }
    const _Float16* bgp[2];
#pragma unroll
    for (int c = 0; c < 2; ++c) {
        int row = (w * 2 + c) * 8 + srow;
        bgp[c] = act + (size_t)(b * NPIX + p0 + row) * KROW + scol;
    }

    f32x4 acc[2][4];
#pragma unroll
    for (int mi = 0; mi < 2; ++mi)
#pragma unroll
        for (int ni = 0; ni < 4; ++ni) acc[mi][ni] = Z4;

    auto STAGE = [&](int kt, _Float16* Asb, _Float16* Bsb) {
#pragma unroll
        for (int c = 0; c < 4; ++c)
            gload16(agp[c] + kt * 64, &Asb[(w * 4 + c) * 512]);
#pragma unroll
        for (int c = 0; c < 2; ++c)
            gload16(bgp[c] + kt * 64, &Bsb[(w * 2 + c) * 512]);
    };

    auto COMPUTE = [&](const _Float16* Asb, const _Float16* Bsb) {
#pragma unroll
        for (int ks = 0; ks < 2; ++ks) {
            half8 av[2], bv[4];
#pragma unroll
            for (int mi = 0; mi < 2; ++mi) {
                const int r = wm + mi * 16 + l15;
                av[mi] = *(const half8*)&Asb[r * 64 + (((ks * 4 + quad) ^ (l15 & 7)) << 3)];
            }
#pragma unroll
            for (int ni = 0; ni < 4; ++ni) {
                const int r = ni * 16 + l15;
                bv[ni] = *(const half8*)&Bsb[r * 64 + (((ks * 4 + quad) ^ (l15 & 7)) << 3)];
            }
#pragma unroll
            for (int mi = 0; mi < 2; ++mi)
#pragma unroll
                for (int ni = 0; ni < 4; ++ni)
                    acc[mi][ni] = MFMA16(av[mi], bv[ni], acc[mi][ni]);
        }
    };

    STAGE(0, As0, Bs0);
    __syncthreads();
    for (int kt2 = 0; kt2 < K / 64; kt2 += 2) {
        STAGE(kt2 + 1, As1, Bs1);
        COMPUTE(As0, Bs0);
        __syncthreads();
        if (kt2 + 2 < K / 64) STAGE(kt2 + 2, As0, Bs0);
        COMPUTE(As1, Bs1);
        __syncthreads();
    }

#pragma unroll
    for (int mi = 0; mi < 2; ++mi) {
#pragma unroll
        for (int r = 0; r < 4; ++r) {
            const int m = m0 + wm + mi * 16 + quad * 4 + r;
            const float bv = bias[m];
#pragma unroll
            for (int ni = 0; ni < 4; ++ni) {
                const int pix = p0 + ni * 16 + l15;
                Cout[(((size_t)(b * M + m)) << 10) + pix] = acc[mi][ni][r] + bv;
            }
        }
    }
}

// ---------------------------------------------------------------------------
// Fused kernel: prep -> gsync -> qkv -> gsync -> attn -> gsync -> out.
// 512 blocks x 256 threads, 64KB LDS union, 2 blocks/CU co-resident.
// qkv: 512 KV units 1:1; 256 Q units on blocks >= 256 (10% tail imbalance).
// ---------------------------------------------------------------------------
__global__ __launch_bounds__(256, 2) void fused_kernel(
    const float* __restrict__ Wq, const float* __restrict__ Wkv,
    const float* __restrict__ Wout, const float* __restrict__ x,
    const float* __restrict__ bout, float* __restrict__ out,
    _Float16* __restrict__ Aq, _Float16* __restrict__ Akv,
    _Float16* __restrict__ Aout, _Float16* __restrict__ xtp,
    _Float16* __restrict__ qt, _Float16* __restrict__ vb,
    _Float16* __restrict__ ktp, _Float16* __restrict__ gout)
{
    __shared__ SMem sm;
    const int bid = blockIdx.x, tid = threadIdx.x;

    // Phase 1: prep (3616 units, grid-stride)
    for (int u = bid; u < 3616; u += NBLK)
        prep_unit(u, tid, &sm, Wq, Wkv, Wout, x, Aq, Akv, Aout, xtp);
    gsync();

    // Phase 2: qkv — KV 1:1; Q overlaid on blocks >= 256
    qkv_unit(false, (bid >> 3) & 7, bid & 7, bid >> 6, tid,
             sm.qk.A0, sm.qk.A1, sm.qk.B0, sm.qk.B1,
             Akv, Aq, xtp, qt, ktp, vb);
    if (bid >= 256) {
        const int qi = bid - 256;
        qkv_unit(true, (qi >> 3) & 3, qi & 7, qi >> 5, tid,
                 sm.qk.A0, sm.qk.A1, sm.qk.B0, sm.qk.B1,
                 Akv, Aq, xtp, qt, ktp, vb);
    }
    gsync();

    // Phase 3: attn (512 units, 1:1)
    attn_unit(bid & 7, bid >> 3, tid, sm.at.Ks, sm.at.Vs, sm.at.Pb,
              qt, ktp, vb, gout);
    gsync();

    // Phase 4: out projection (256 units on blocks < 256)
    if (bid < 256)
        out_unit(bid & 15, (bid >> 4) & 1, bid >> 5, tid,
                 sm.op.A0, sm.op.A1, sm.op.B0, sm.op.B1,
                 Aout, gout, out, bout);
}

// ---------------------------------------------------------------------------
// Workspace (f16 units, ~43.4 MB):
//   xtp 2.37M | Aq 128K | Akv 2.25M | Aout 128K | qt 4M | vb 4M | ktp 4M | gout 4M
// 1 plain dispatch (graph-capture-safe; no cooperative API).
// ---------------------------------------------------------------------------
extern "C" void kernel_launch(void* const* d_in, const int* in_sizes, int n_in,
                              void* d_out, int out_size, void* d_ws, size_t ws_size,
                              hipStream_t stream)
{
    const float* x    = (const float*)d_in[0];
    const float* Wq   = (const float*)d_in[1];
    const float* Wkv  = (const float*)d_in[2];
    const float* Wout = (const float*)d_in[3];
    const float* bout = (const float*)d_in[4];
    float* out = (float*)d_out;

    _Float16* xtp  = (_Float16*)d_ws;
    _Float16* Aq   = xtp  + (size_t)BATCH * PPIX * DIM;
    _Float16* Akv  = Aq   + (size_t)INNER * DIM;
    _Float16* Aout = Akv  + (size_t)KVCH * 2304;
    _Float16* qt   = Aout + (size_t)DIM * INNER;
    _Float16* vb   = qt   + (size_t)BATCH * NPIX * INNER;
    _Float16* ktp  = vb   + (size_t)BATCH * NPIX * INNER;
    _Float16* gout = ktp  + (size_t)BATCH * NPIX * INNER;

    fused_kernel<<<NBLK, 256, 0, stream>>>(
        Wq, Wkv, Wout, x, bout, out, Aq, Akv, Aout, xtp, qt, vb, ktp, gout);
}

// Round 10
// 183.881 us; speedup vs baseline: 2.5103x; 2.5103x over previous
//
#include <hip/hip_runtime.h>
#include <math.h>

// Attention_5471788335537 on gfx950: b=8, dim=256, 32x32, heads=8, dhead=64.
// Round 19: FULL REVERT to r17 (168.05us session best) + ONE change: qkv
// block->XCD locality swizzle (catalog T1). qkv grid flattened to 768 (=96/XCD,
// all resident at 3 blocks/CU); decode puts a 3-mt x 4-batch rectangle of
// (A-slab, xtp-batch) pairs on each XCD: per-XCD L2 working set 11.6MB ->
// ~4.1MB (~L2-resident staging instead of L3-served). Bijective (768%8==0);
// pure index permutation, zero numerics risk.
// Ledger (dead ends, do not retry): r10 96KB qkv LDS -> 1 wave/SIMD; r11
// B-direct -> uncoalesced 512B lanes; r12 cooperative launch -> capture
// crash; r15 vmcnt(N)+sched_barrier(0) -> -8us (order-pinning, m141);
// r18 software-barrier fusion -> 414us (unbacked-off spin poisons fabric
// during phase imbalance). Dispatch gaps (~70us) = unreachable here.
// qkv noise band +-5us; absmax sits AT 0.015625 — numerics must not change.
#define BATCH 8
#define DIM   256
#define NPIX  1024
#define DHEAD 64
#define INNER 512
#define KVCH  1024
#define PPIX  1156   // 34*34 padded pixels

typedef _Float16 half8 __attribute__((ext_vector_type(8)));
typedef _Float16 half4 __attribute__((ext_vector_type(4)));
typedef float    f32x4 __attribute__((ext_vector_type(4)));
typedef float    f32x16 __attribute__((ext_vector_type(16)));
#define MFMA16(a, b, c) __builtin_amdgcn_mfma_f32_16x16x32_f16(a, b, c, 0, 0, 0)
#define MFMA32(a, b, c) __builtin_amdgcn_mfma_f32_32x32x16_f16(a, b, c, 0, 0, 0)

static __device__ __forceinline__ float gelu_f(float v) {
    return 0.5f * v * (1.0f + erff(v * 0.70710678118654752440f));
}

static __device__ __forceinline__ void gload16(const _Float16* g, _Float16* l) {
    __builtin_amdgcn_global_load_lds(
        (const __attribute__((address_space(1))) unsigned int*)g,
        (__attribute__((address_space(3))) unsigned int*)l, 16, 0, 0);
}

// ---------------------------------------------------------------------------
// Fused prep, r17 block map (3616 blocks):
//   [0,512)      transpose x -> padded xtp interior
//   [512,1024)   Wq -> f16 (coalesced 1:1)
//   [1024,2048)  Wkv reorder via LDS slab (coalesced both sides; stride-9
//                LDS reads, 9 coprime 32 banks -> conflict-free)
//   [2048,2560)  Wout -> f16 (coalesced 1:1)
//   [2560,3616)  zero xtp halo
// ---------------------------------------------------------------------------
__global__ __launch_bounds__(256) void prep_kernel(
    const float* __restrict__ Wq, const float* __restrict__ Wkv,
    const float* __restrict__ Wout, const float* __restrict__ x,
    _Float16* __restrict__ Aq, _Float16* __restrict__ Akv,
    _Float16* __restrict__ Aout, _Float16* __restrict__ xtp)
{
    const int bid = blockIdx.x, tid = threadIdx.x;
    if (bid < 512) {
        __shared__ float ts[64][65];
        const int pt = (bid & 15) * 64, ic0 = ((bid >> 4) & 3) * 64, b = bid >> 6;
        const float* xb = x + (((size_t)(b * DIM + ic0)) << 10) + pt;
#pragma unroll
        for (int e = tid; e < 4096; e += 256) {
            int i = e >> 6, p = e & 63;
            ts[i][p] = xb[((size_t)i << 10) + p];
        }
        __syncthreads();
#pragma unroll
        for (int e = tid; e < 512; e += 256) {
            int p = e >> 3, ig = e & 7;
            int gp = pt + p, y = gp >> 5, xc = gp & 31;
            half8 v;
#pragma unroll
            for (int u = 0; u < 8; ++u) v[u] = (_Float16)ts[ig * 8 + u][p];
            *(half8*)&xtp[((size_t)b * PPIX + (y + 1) * 34 + xc + 1) * 256 + ic0 + ig * 8] = v;
        }
    } else if (bid < 1024) {
        const int e = (bid - 512) * 256 + tid;     // [0,131072) exact
        Aq[e] = (_Float16)Wq[e];
    } else if (bid < 2048) {
        __shared__ float slab[2304];
        const int oc = bid - 1024;
        const float* src = Wkv + (size_t)oc * 2304;
#pragma unroll
        for (int j = tid; j < 2304; j += 256) slab[j] = src[j];
        __syncthreads();
        _Float16* dst = Akv + (size_t)oc * 2304;
#pragma unroll
        for (int j = tid; j < 2304; j += 256) {
            const int ic = j & 255, s = j >> 8;    // j = s*256 + ic
            dst[j] = (_Float16)slab[ic * 9 + s];
        }
    } else if (bid < 2560) {
        const int e = (bid - 2048) * 256 + tid;    // [0,131072) exact
        Aout[e] = (_Float16)Wout[e];
    } else {
        const int he = (bid - 2560) * 256 + tid;   // [0,270336) exact
        int b = he / 33792;                        // 132*256 per batch
        int r = he - b * 33792;
        int hp = r >> 8, ic = r & 255;
        int row, col;
        if (hp < 34)      { row = 0;  col = hp; }
        else if (hp < 68) { row = 33; col = hp - 34; }
        else { int k2 = hp - 68; row = 1 + (k2 >> 1); col = (k2 & 1) * 33; }
        xtp[((size_t)b * PPIX + row * 34 + col) * 256 + ic] = (_Float16)0.f;
    }
}

// ---------------------------------------------------------------------------
// Fused q + kv implicit GEMM, 32x32x16 MFMA, tile 128x128, waves 2x2.
// Round 19: 1-D grid 768 with XCD-locality decode (T1). Assuming dispatch
// round-robins consecutive ids across 8 XCDs (HK/m157 heuristic; if wrong,
// this is merely a permutation = neutral):
//   xcd = id&7, j = id>>3, nt = j&7, q = j>>3 (0..11)
//   mt12 = (xcd&3)*3 + q%3   (each XCD: 3 consecutive mt values)
//   b    = (xcd>>2)*4 + q/3  (each XCD: 4 consecutive batches)
// -> per-XCD working set = 3 A-slabs + 4 xtp batches ~= 4.1MB ~ L2.
// mt12<8: A=Akv (36 kts); mt12<4 -> K headwise, 4..7 -> V channel-major.
// mt12>=8: A=Aq (4 kts), q*0.125 -> qt headwise.
// r14 schedule (best): dbuf, pairwise kt unroll, STAGE(next)->COMPUTE(cur)
// ->__syncthreads. XOR-chunk staging swizzle; frag reads conflict-free.
// ---------------------------------------------------------------------------
__global__ __launch_bounds__(256) void qkv_gemm_kernel(
    const _Float16* __restrict__ Akv, const _Float16* __restrict__ Aq,
    const _Float16* __restrict__ xtp, _Float16* __restrict__ qt,
    _Float16* __restrict__ ktp, _Float16* __restrict__ vb)
{
    __shared__ _Float16 As0[128 * 64];   // 16 KB
    __shared__ _Float16 As1[128 * 64];   // 16 KB
    __shared__ _Float16 Bs0[128 * 64];   // 16 KB
    __shared__ _Float16 Bs1[128 * 64];   // 16 KB
    const int id = blockIdx.x;
    const int xcd = id & 7, j = id >> 3;
    const int nt = j & 7, q12 = j >> 3;              // q12 in [0,12)
    const int mt12 = (xcd & 3) * 3 + (q12 % 3);      // [0,12)
    const int b    = (xcd >> 2) * 4 + (q12 / 3);     // [0,8)
    const bool QBLK = (mt12 >= 8);
    const int tid = threadIdx.x;
    const int w = tid >> 6, lane = tid & 63;
    const int l31 = lane & 31, kh = lane >> 5;
    const int m0 = (QBLK ? mt12 - 8 : mt12) * 128, p0 = nt * 128;
    const int wm = (w >> 1) * 64, wn = (w & 1) * 64;

    const int srow = lane >> 3;
    const int scol = ((lane & 7) ^ srow) * 8;

    const _Float16* abase = QBLK ? Aq : Akv;
    const int astride = QBLK ? 256 : 2304;
    const int ktend = QBLK ? 4 : 36;   // both even (pairwise unroll relies on it)

    const _Float16* agp[4];
    const _Float16* bgp[4];
#pragma unroll
    for (int c = 0; c < 4; ++c) {
        int row = (w * 4 + c) * 8 + srow;
        agp[c] = abase + (size_t)(m0 + row) * astride + scol;
        int p = p0 + row, py = p >> 5, px = p & 31;
        bgp[c] = xtp + ((size_t)b * PPIX + (py + 1) * 34 + px + 1) * 256 + scol;
    }

    f32x16 acc[2][2];
#pragma unroll
    for (int mf = 0; mf < 2; ++mf)
#pragma unroll
        for (int nf = 0; nf < 2; ++nf)
#pragma unroll
            for (int r = 0; r < 16; ++r) acc[mf][nf][r] = 0.f;

    auto STAGE = [&](int kt, _Float16* Asb, _Float16* Bsb) {
        const int s = QBLK ? 4 : (kt >> 2);
        const int doff = (s / 3 - 1) * 34 + (s - (s / 3) * 3) - 1;   // dy*34+dx
        const int boff = doff * 256 + (kt & 3) * 64;                 // wave-uniform
#pragma unroll
        for (int c = 0; c < 4; ++c)
            gload16(agp[c] + kt * 64, &Asb[(w * 4 + c) * 512]);
#pragma unroll
        for (int c = 0; c < 4; ++c)
            gload16(bgp[c] + boff, &Bsb[(w * 4 + c) * 512]);
    };

    auto COMPUTE = [&](const _Float16* Asb, const _Float16* Bsb) {
#pragma unroll
        for (int kc = 0; kc < 4; ++kc) {
            const int cx = ((((kc << 1) | kh) ^ (l31 & 7)) << 3);
            half8 af[2], bf[2];
#pragma unroll
            for (int mf = 0; mf < 2; ++mf)
                af[mf] = *(const half8*)&Asb[(wm + mf * 32 + l31) * 64 + cx];
#pragma unroll
            for (int nf = 0; nf < 2; ++nf)
                bf[nf] = *(const half8*)&Bsb[(wn + nf * 32 + l31) * 64 + cx];
#pragma unroll
            for (int mf = 0; mf < 2; ++mf)
#pragma unroll
                for (int nf = 0; nf < 2; ++nf)
                    acc[mf][nf] = MFMA32(af[mf], bf[nf], acc[mf][nf]);
        }
    };

    // prologue: stage kt=0 into buffer 0; single drain+barrier
    STAGE(0, As0, Bs0);
    __syncthreads();

    for (int kt2 = 0; kt2 < ktend; kt2 += 2) {
        // even kt: prefetch kt2+1 into buf1, compute buf0
        STAGE(kt2 + 1, As1, Bs1);
        COMPUTE(As0, Bs0);
        __syncthreads();   // drains prefetch (landed under COMPUTE) + swap
        // odd kt: prefetch kt2+2 into buf0, compute buf1
        if (kt2 + 2 < ktend) STAGE(kt2 + 2, As0, Bs0);
        COMPUTE(As1, Bs1);
        __syncthreads();
    }

#pragma unroll
    for (int mf = 0; mf < 2; ++mf) {
        const int mbase = m0 + wm + mf * 32;   // multiple of 32
        if (!QBLK && mbase >= 512) {
            // V: f16 channel-major [(b*512 + m-512)<<10 + pix]
#pragma unroll
            for (int nf = 0; nf < 2; ++nf) {
                const int pix = p0 + wn + nf * 32 + l31;
#pragma unroll
                for (int reg = 0; reg < 16; ++reg) {
                    const int mv = mbase - 512 + (reg & 3) + 8 * (reg >> 2) + 4 * kh;
                    vb[(((size_t)(b * 512 + mv)) << 10) + pix] =
                        (_Float16)acc[mf][nf][reg];
                }
            }
        } else {
            // headwise: [(b*8+h)<<10 + pix][64], d contiguous in groups of 4
            const int h = mbase >> 6;
            const int dbase = (mbase & 63) + kh * 4;
            _Float16* dst = QBLK ? qt : ktp;
#pragma unroll
            for (int nf = 0; nf < 2; ++nf) {
                const int pix = p0 + wn + nf * 32 + l31;
#pragma unroll
                for (int g = 0; g < 4; ++g) {
                    half4 v4;
#pragma unroll
                    for (int r = 0; r < 4; ++r) {
                        float vv = acc[mf][nf][g * 4 + r];
                        if (QBLK) vv *= 0.125f;
                        v4[r] = (_Float16)vv;
                    }
                    *(half4*)&dst[((((size_t)(b * 8 + h)) << 10) + pix) * 64 + dbase + g * 8] = v4;
                }
            }
        }
    }
}

// ---------------------------------------------------------------------------
// Output projection GEMM (16x16x32, tile 128M x 64N, 256 blocks).
// r16/r17: dbuf (As0/As1, Bs0/Bs1; 48KB LDS), STAGE(next)->COMPUTE(cur)->sync.
// ---------------------------------------------------------------------------
template<int M, int K, int KROW>
__global__ __launch_bounds__(256) void out_gemm_kernel(
    const _Float16* __restrict__ A, const _Float16* __restrict__ act,
    float* __restrict__ Cout, const float* __restrict__ bias)
{
    __shared__ _Float16 As0[128 * 64];
    __shared__ _Float16 As1[128 * 64];
    __shared__ _Float16 Bs0[64 * 64];
    __shared__ _Float16 Bs1[64 * 64];
    const int nt = blockIdx.x, mt = blockIdx.y, b = blockIdx.z;
    const int tid = threadIdx.x;
    const int w = tid >> 6, lane = tid & 63;
    const int quad = lane >> 4, l15 = lane & 15;
    const int m0 = mt * 128, p0 = nt * 64;
    const int wm = w * 32;
    const f32x4 Z4 = {0.f, 0.f, 0.f, 0.f};

    const int srow = lane >> 3;
    const int scol = ((lane & 7) ^ srow) * 8;

    const _Float16* agp[4];
#pragma unroll
    for (int c = 0; c < 4; ++c) {
        int row = (w * 4 + c) * 8 + srow;
        agp[c] = A + (size_t)(m0 + row) * K + scol;
    }
    const _Float16* bgp[2];
#pragma unroll
    for (int c = 0; c < 2; ++c) {
        int row = (w * 2 + c) * 8 + srow;
        bgp[c] = act + (size_t)(b * NPIX + p0 + row) * KROW + scol;
    }

    f32x4 acc[2][4];
#pragma unroll
    for (int mi = 0; mi < 2; ++mi)
#pragma unroll
        for (int ni = 0; ni < 4; ++ni) acc[mi][ni] = Z4;

    auto STAGE = [&](int kt, _Float16* Asb, _Float16* Bsb) {
#pragma unroll
        for (int c = 0; c < 4; ++c)
            gload16(agp[c] + kt * 64, &Asb[(w * 4 + c) * 512]);
#pragma unroll
        for (int c = 0; c < 2; ++c)
            gload16(bgp[c] + kt * 64, &Bsb[(w * 2 + c) * 512]);
    };

    auto COMPUTE = [&](const _Float16* Asb, const _Float16* Bsb) {
#pragma unroll
        for (int ks = 0; ks < 2; ++ks) {
            half8 av[2], bv[4];
#pragma unroll
            for (int mi = 0; mi < 2; ++mi) {
                const int r = wm + mi * 16 + l15;
                av[mi] = *(const half8*)&Asb[r * 64 + (((ks * 4 + quad) ^ (l15 & 7)) << 3)];
            }
#pragma unroll
            for (int ni = 0; ni < 4; ++ni) {
                const int r = ni * 16 + l15;
                bv[ni] = *(const half8*)&Bsb[r * 64 + (((ks * 4 + quad) ^ (l15 & 7)) << 3)];
            }
#pragma unroll
            for (int mi = 0; mi < 2; ++mi)
#pragma unroll
                for (int ni = 0; ni < 4; ++ni)
                    acc[mi][ni] = MFMA16(av[mi], bv[ni], acc[mi][ni]);
        }
    };

    STAGE(0, As0, Bs0);
    __syncthreads();
    for (int kt2 = 0; kt2 < K / 64; kt2 += 2) {
        STAGE(kt2 + 1, As1, Bs1);
        COMPUTE(As0, Bs0);
        __syncthreads();
        if (kt2 + 2 < K / 64) STAGE(kt2 + 2, As0, Bs0);
        COMPUTE(As1, Bs1);
        __syncthreads();
    }

#pragma unroll
    for (int mi = 0; mi < 2; ++mi) {
#pragma unroll
        for (int r = 0; r < 4; ++r) {
            const int m = m0 + wm + mi * 16 + quad * 4 + r;
            const float bv = bias[m];
#pragma unroll
            for (int ni = 0; ni < 4; ++ni) {
                const int pix = p0 + ni * 16 + l15;
                Cout[(((size_t)(b * M + m)) << 10) + pix] = acc[mi][ni][r] + bv;
            }
        }
    }
}

// ---------------------------------------------------------------------------
// Attention (r16/r17): K double-buffered (Ks0/Ks1), V retimed into the QK^T
// shadow. Per kt: QKT(K[cur]) -> sync -> issue K(kt+1)->K[other] (flies
// under P-write+PV) -> PV(Vs) -> sync -> issue V(kt+1) (flies under next
// QKT). LDS 80KB -> 2 blocks/CU. Numerics identical to round-6 structure.
// ---------------------------------------------------------------------------
__global__ __launch_bounds__(256) void attn_kernel(
    const _Float16* __restrict__ qt,   // [(b*8+h)<<10 + pix]*64 + d, pre-scaled
    const _Float16* __restrict__ ktp,  // (bh<<16) + pix*64 + d
    const _Float16* __restrict__ vbb,  // [(b*512 + h*64 + d)<<10] + pix
    _Float16* __restrict__ gout)       // [b*1024+pix][512]
{
    __shared__ _Float16 Ks0[128 * 64];   // 16 KB
    __shared__ _Float16 Ks1[128 * 64];   // 16 KB
    __shared__ _Float16 Vs[64 * 128];    // 16 KB
    __shared__ _Float16 Pb[128 * 128];   // 32 KB
    const int qtile = blockIdx.x, bh = blockIdx.y;
    const int b = bh >> 3, h = bh & 7;
    const int p0 = qtile * 128;
    const int tid = threadIdx.x;
    const int w = tid >> 6, lane = tid & 63;
    const int quad = lane >> 4, l15 = lane & 15;
    const f32x4 Z4 = {0.f, 0.f, 0.f, 0.f};

    half8 ones;
#pragma unroll
    for (int u = 0; u < 8; ++u) ones[u] = (_Float16)1.0f;

    half8 qf[2][2];
    {
        const _Float16* qrow =
            qt + ((((size_t)(bh)) << 10) + p0 + w * 32 + l15) * 64;
#pragma unroll
        for (int iff = 0; iff < 2; ++iff)
#pragma unroll
            for (int ks = 0; ks < 2; ++ks)
                qf[iff][ks] = *(const half8*)(qrow + iff * 16 * 64 + ks * 32 + quad * 8);
    }

    const _Float16* kbase = ktp + ((size_t)bh << 16);
    const _Float16* vbase = vbb + (((size_t)(b * 512 + h * 64)) << 10);

    f32x4 oacc[4][2];
#pragma unroll
    for (int mf = 0; mf < 4; ++mf)
#pragma unroll
        for (int iff = 0; iff < 2; ++iff) oacc[mf][iff] = Z4;
    f32x4 racc[2] = {Z4, Z4};

    const int kchunk = (lane & 7) ^ (lane >> 3);

    auto STAGE_K = [&](int kt, _Float16* Kb) {
        const _Float16* kg = kbase + (size_t)(kt * 128) * 64;
#pragma unroll
        for (int i = 0; i < 4; ++i) {
            const int t = i * 4 + w;
            gload16(kg + (t * 8 + (lane >> 3)) * 64 + kchunk * 8, &Kb[t * 512]);
        }
    };
    auto STAGE_V = [&](int kt) {
        const int pk = kt * 128;
#pragma unroll
        for (int i = 0; i < 4; ++i) {
            const int t = i * 4 + w;
            const int vd = t * 4 + (lane >> 4);
            gload16(vbase + ((size_t)vd << 10) + pk + (((lane & 15) ^ (vd & 15)) << 3),
                    &Vs[t * 512]);
        }
    };
    auto QKT = [&](const _Float16* Kb) {
#pragma unroll
        for (int g = 0; g < 2; ++g) {
            f32x4 s[4][2];
#pragma unroll
            for (int jf2 = 0; jf2 < 4; ++jf2) {
                const int jr = (g * 4 + jf2) * 16 + l15;
                const half8 ka0 = *(const half8*)&Kb[jr * 64 + ((quad ^ (l15 & 7)) << 3)];
                const half8 ka1 = *(const half8*)&Kb[jr * 64 + (((4 + quad) ^ (l15 & 7)) << 3)];
#pragma unroll
                for (int iff = 0; iff < 2; ++iff) {
                    s[jf2][iff] = MFMA16(ka0, qf[iff][0], Z4);
                    s[jf2][iff] = MFMA16(ka1, qf[iff][1], s[jf2][iff]);
                }
            }
#pragma unroll
            for (int jf2 = 0; jf2 < 4; ++jf2) {
#pragma unroll
                for (int iff = 0; iff < 2; ++iff) {
                    half4 pv4;
#pragma unroll
                    for (int r = 0; r < 4; ++r)
                        pv4[r] = (_Float16)__expf(s[jf2][iff][r] - 8.0f);
                    const int i = w * 32 + iff * 16 + l15;
                    const int c = ((g * 4 + jf2) << 1) + (quad >> 1);
                    *(half4*)&Pb[i * 128 + ((c ^ l15) << 3) + ((quad & 1) << 2)] = pv4;
                }
            }
        }
    };
    auto PV = [&]() {
#pragma unroll
        for (int kc = 0; kc < 4; ++kc) {
            half8 bv[2];
#pragma unroll
            for (int iff = 0; iff < 2; ++iff) {
                const int i = w * 32 + iff * 16 + l15;
                bv[iff] = *(const half8*)&Pb[i * 128 + (((kc * 4 + quad) ^ l15) << 3)];
                racc[iff] = MFMA16(ones, bv[iff], racc[iff]);
            }
#pragma unroll
            for (int mf = 0; mf < 4; ++mf) {
                const int vr = mf * 16 + l15;
                const half8 va = *(const half8*)&Vs[vr * 128 + (((kc * 4 + quad) ^ l15) << 3)];
#pragma unroll
                for (int iff = 0; iff < 2; ++iff)
                    oacc[mf][iff] = MFMA16(va, bv[iff], oacc[mf][iff]);
            }
        }
    };

    // prologue: K0 + V0 staged, drained once
    STAGE_K(0, Ks0);
    STAGE_V(0);
    __syncthreads();

    for (int kt2 = 0; kt2 < 8; kt2 += 2) {
        // even kt = kt2: K in Ks0, V(kt2) in Vs
        QKT(Ks0);
        __syncthreads();               // Ks0 reads done; drains V(kt2) prefetch
        STAGE_K(kt2 + 1, Ks1);         // flies under P-write + PV
        PV();
        __syncthreads();               // Vs reads done; drains K(kt2+1)
        STAGE_V(kt2 + 1);              // flies under next QKT
        // odd kt = kt2+1: K in Ks1
        QKT(Ks1);
        __syncthreads();               // Ks1 reads done; drains V(kt2+1)
        if (kt2 + 2 < 8) STAGE_K(kt2 + 2, Ks0);
        PV();
        __syncthreads();               // Vs reads done; drains K(kt2+2)
        if (kt2 + 2 < 8) STAGE_V(kt2 + 2);
    }

    float rinv[2];
#pragma unroll
    for (int iff = 0; iff < 2; ++iff) rinv[iff] = 1.f / racc[iff][0];

    __syncthreads();
    _Float16* scr = Pb;  // [128 rows][72 halves]
#pragma unroll
    for (int mf = 0; mf < 4; ++mf) {
#pragma unroll
        for (int iff = 0; iff < 2; ++iff) {
            half4 o4;
#pragma unroll
            for (int r = 0; r < 4; ++r)
                o4[r] = (_Float16)gelu_f(oacc[mf][iff][r] * rinv[iff]);
            const int i = w * 32 + iff * 16 + l15;
            *(half4*)&scr[i * 72 + mf * 16 + quad * 4] = o4;
        }
    }
    __syncthreads();
    _Float16* go = gout + ((size_t)(b * NPIX + p0)) * INNER + h * 64;
#pragma unroll
    for (int it = 0; it < 4; ++it) {
        const int e = tid + it * 256;
        const int p = e >> 3, dg = e & 7;
        *(half8*)(go + (size_t)p * INNER + dg * 8) = *(const half8*)&scr[p * 72 + dg * 8];
    }
}

// ---------------------------------------------------------------------------
// Workspace (f16 units, ~43.4 MB):
//   xtp 2.37M | Aq 128K | Akv 2.25M | Aout 128K | qt 4M | vb 4M | ktp 4M | gout 4M
// 4 dispatches: prep, qkv (768 flat, XCD-swizzled), attn, out.
// ---------------------------------------------------------------------------
extern "C" void kernel_launch(void* const* d_in, const int* in_sizes, int n_in,
                              void* d_out, int out_size, void* d_ws, size_t ws_size,
                              hipStream_t stream)
{
    const float* x    = (const float*)d_in[0];
    const float* Wq   = (const float*)d_in[1];
    const float* Wkv  = (const float*)d_in[2];
    const float* Wout = (const float*)d_in[3];
    const float* bout = (const float*)d_in[4];
    float* out = (float*)d_out;

    _Float16* xtp  = (_Float16*)d_ws;
    _Float16* Aq   = xtp  + (size_t)BATCH * PPIX * DIM;
    _Float16* Akv  = Aq   + (size_t)INNER * DIM;
    _Float16* Aout = Akv  + (size_t)KVCH * 2304;
    _Float16* qt   = Aout + (size_t)DIM * INNER;
    _Float16* vb   = qt   + (size_t)BATCH * NPIX * INNER;
    _Float16* ktp  = vb   + (size_t)BATCH * NPIX * INNER;
    _Float16* gout = ktp  + (size_t)BATCH * NPIX * INNER;

    prep_kernel<<<3616, 256, 0, stream>>>(Wq, Wkv, Wout, x, Aq, Akv, Aout, xtp);
    qkv_gemm_kernel<<<768, 256, 0, stream>>>(Akv, Aq, xtp, qt, ktp, vb);
    attn_kernel<<<dim3(8, 64), 256, 0, stream>>>(qt, ktp, vb, gout);
    out_gemm_kernel<DIM, 512, 512>
        <<<dim3(16, 2, BATCH), 256, 0, stream>>>(Aout, gout, out, bout);
}

// Round 11
// 163.131 us; speedup vs baseline: 2.8296x; 1.1272x over previous
//
#include <hip/hip_runtime.h>
#include <math.h>

// Attention_5471788335537 on gfx950: b=8, dim=256, 32x32, heads=8, dhead=64.
// Round 20: r19's XCD swizzle CONFIRMED the dispatch model (FETCH 34.5->17.4MB
// = same-id&7 blocks share an XCD) but had a decode bug: XCDs 3,7 got ALL
// Q-blocks (4kt) -> 9x work imbalance -> 57.5*8/6 = 76us (measured 76).
// Fix: balanced bijective partition, 2432 kt/XCD uniform:
//   KV: XCD x owns mt-pair {2(x&3),2(x&3)+1} x batch-quad {4(x>>2)..+3} x nt
//       (64 units); Q: XCD x owns b=x, all 4 qmt x 8 nt (32 units).
// Per-XCD read set: 2 Akv slabs + 4 xtp batches + Aq ~= 3.8MB < 4MB L2.
// All else identical to r17 (168.05us session best).
// Ledger (dead, do not retry): r10 96KB qkv LDS -> 1 wave/SIMD; r11 B-direct
// -> uncoalesced; r12 cooperative -> capture crash; r15 vmcnt(N)+SB(0) ->
// order-pinning -8us; r18 spin-barrier fusion -> 414us fabric poison;
// dispatch gaps (~70us) unreachable. qkv noise +-5us; absmax AT 0.015625.
#define BATCH 8
#define DIM   256
#define NPIX  1024
#define DHEAD 64
#define INNER 512
#define KVCH  1024
#define PPIX  1156   // 34*34 padded pixels

typedef _Float16 half8 __attribute__((ext_vector_type(8)));
typedef _Float16 half4 __attribute__((ext_vector_type(4)));
typedef float    f32x4 __attribute__((ext_vector_type(4)));
typedef float    f32x16 __attribute__((ext_vector_type(16)));
#define MFMA16(a, b, c) __builtin_amdgcn_mfma_f32_16x16x32_f16(a, b, c, 0, 0, 0)
#define MFMA32(a, b, c) __builtin_amdgcn_mfma_f32_32x32x16_f16(a, b, c, 0, 0, 0)

static __device__ __forceinline__ float gelu_f(float v) {
    return 0.5f * v * (1.0f + erff(v * 0.70710678118654752440f));
}

static __device__ __forceinline__ void gload16(const _Float16* g, _Float16* l) {
    __builtin_amdgcn_global_load_lds(
        (const __attribute__((address_space(1))) unsigned int*)g,
        (__attribute__((address_space(3))) unsigned int*)l, 16, 0, 0);
}

// ---------------------------------------------------------------------------
// Fused prep, r17 block map (3616 blocks):
//   [0,512)      transpose x -> padded xtp interior
//   [512,1024)   Wq -> f16 (coalesced 1:1)
//   [1024,2048)  Wkv reorder via LDS slab (coalesced both sides; stride-9
//                LDS reads, 9 coprime 32 banks -> conflict-free)
//   [2048,2560)  Wout -> f16 (coalesced 1:1)
//   [2560,3616)  zero xtp halo
// ---------------------------------------------------------------------------
__global__ __launch_bounds__(256) void prep_kernel(
    const float* __restrict__ Wq, const float* __restrict__ Wkv,
    const float* __restrict__ Wout, const float* __restrict__ x,
    _Float16* __restrict__ Aq, _Float16* __restrict__ Akv,
    _Float16* __restrict__ Aout, _Float16* __restrict__ xtp)
{
    const int bid = blockIdx.x, tid = threadIdx.x;
    if (bid < 512) {
        __shared__ float ts[64][65];
        const int pt = (bid & 15) * 64, ic0 = ((bid >> 4) & 3) * 64, b = bid >> 6;
        const float* xb = x + (((size_t)(b * DIM + ic0)) << 10) + pt;
#pragma unroll
        for (int e = tid; e < 4096; e += 256) {
            int i = e >> 6, p = e & 63;
            ts[i][p] = xb[((size_t)i << 10) + p];
        }
        __syncthreads();
#pragma unroll
        for (int e = tid; e < 512; e += 256) {
            int p = e >> 3, ig = e & 7;
            int gp = pt + p, y = gp >> 5, xc = gp & 31;
            half8 v;
#pragma unroll
            for (int u = 0; u < 8; ++u) v[u] = (_Float16)ts[ig * 8 + u][p];
            *(half8*)&xtp[((size_t)b * PPIX + (y + 1) * 34 + xc + 1) * 256 + ic0 + ig * 8] = v;
        }
    } else if (bid < 1024) {
        const int e = (bid - 512) * 256 + tid;     // [0,131072) exact
        Aq[e] = (_Float16)Wq[e];
    } else if (bid < 2048) {
        __shared__ float slab[2304];
        const int oc = bid - 1024;
        const float* src = Wkv + (size_t)oc * 2304;
#pragma unroll
        for (int j = tid; j < 2304; j += 256) slab[j] = src[j];
        __syncthreads();
        _Float16* dst = Akv + (size_t)oc * 2304;
#pragma unroll
        for (int j = tid; j < 2304; j += 256) {
            const int ic = j & 255, s = j >> 8;    // j = s*256 + ic
            dst[j] = (_Float16)slab[ic * 9 + s];
        }
    } else if (bid < 2560) {
        const int e = (bid - 2048) * 256 + tid;    // [0,131072) exact
        Aout[e] = (_Float16)Wout[e];
    } else {
        const int he = (bid - 2560) * 256 + tid;   // [0,270336) exact
        int b = he / 33792;                        // 132*256 per batch
        int r = he - b * 33792;
        int hp = r >> 8, ic = r & 255;
        int row, col;
        if (hp < 34)      { row = 0;  col = hp; }
        else if (hp < 68) { row = 33; col = hp - 34; }
        else { int k2 = hp - 68; row = 1 + (k2 >> 1); col = (k2 & 1) * 33; }
        xtp[((size_t)b * PPIX + row * 34 + col) * 256 + ic] = (_Float16)0.f;
    }
}

// ---------------------------------------------------------------------------
// Fused q + kv implicit GEMM, 32x32x16 MFMA, tile 128x128, waves 2x2.
// Round 20: 1-D grid 768, BALANCED XCD-locality decode (id&7 -> XCD is
// measured, r19 FETCH halving):
//   x = id&7, r = id>>3 (96 units/XCD, 2432 kt/XCD uniform)
//   r<64 (KV): nt=r&7, mtl=2*(x&3)+((r>>3)&1), b=4*(x>>2)+(r>>4)
//   r>=64 (Q): qidx=r-64, nt=qidx&7, qmt=qidx>>3, b=x
// KV mtl<4 -> K headwise, 4..7 -> V channel-major; Q (4 kts) q*0.125 -> qt.
// r14 schedule (best): dbuf, pairwise kt unroll, STAGE(next)->COMPUTE(cur)
// ->__syncthreads. XOR-chunk staging swizzle; frag reads conflict-free.
// ---------------------------------------------------------------------------
__global__ __launch_bounds__(256) void qkv_gemm_kernel(
    const _Float16* __restrict__ Akv, const _Float16* __restrict__ Aq,
    const _Float16* __restrict__ xtp, _Float16* __restrict__ qt,
    _Float16* __restrict__ ktp, _Float16* __restrict__ vb)
{
    __shared__ _Float16 As0[128 * 64];   // 16 KB
    __shared__ _Float16 As1[128 * 64];   // 16 KB
    __shared__ _Float16 Bs0[128 * 64];   // 16 KB
    __shared__ _Float16 Bs1[128 * 64];   // 16 KB
    const int id = blockIdx.x;
    const int x = id & 7, r = id >> 3;               // x = XCD slot, r in [0,96)
    int mtl, nt, b;
    bool QBLK;
    if (r < 64) {                                    // KV: 64 units/XCD
        QBLK = false;
        nt  = r & 7;
        mtl = 2 * (x & 3) + ((r >> 3) & 1);          // [0,8)
        b   = 4 * (x >> 2) + (r >> 4);               // [0,8)
    } else {                                         // Q: 32 units/XCD
        QBLK = true;
        const int qidx = r - 64;
        nt  = qidx & 7;
        mtl = qidx >> 3;                             // [0,4)
        b   = x;                                     // b = x (in x's batch quad)
    }
    const int tid = threadIdx.x;
    const int w = tid >> 6, lane = tid & 63;
    const int l31 = lane & 31, kh = lane >> 5;
    const int m0 = mtl * 128, p0 = nt * 128;
    const int wm = (w >> 1) * 64, wn = (w & 1) * 64;

    const int srow = lane >> 3;
    const int scol = ((lane & 7) ^ srow) * 8;

    const _Float16* abase = QBLK ? Aq : Akv;
    const int astride = QBLK ? 256 : 2304;
    const int ktend = QBLK ? 4 : 36;   // both even (pairwise unroll relies on it)

    const _Float16* agp[4];
    const _Float16* bgp[4];
#pragma unroll
    for (int c = 0; c < 4; ++c) {
        int row = (w * 4 + c) * 8 + srow;
        agp[c] = abase + (size_t)(m0 + row) * astride + scol;
        int p = p0 + row, py = p >> 5, px = p & 31;
        bgp[c] = xtp + ((size_t)b * PPIX + (py + 1) * 34 + px + 1) * 256 + scol;
    }

    f32x16 acc[2][2];
#pragma unroll
    for (int mf = 0; mf < 2; ++mf)
#pragma unroll
        for (int nf = 0; nf < 2; ++nf)
#pragma unroll
            for (int rr = 0; rr < 16; ++rr) acc[mf][nf][rr] = 0.f;

    auto STAGE = [&](int kt, _Float16* Asb, _Float16* Bsb) {
        const int s = QBLK ? 4 : (kt >> 2);
        const int doff = (s / 3 - 1) * 34 + (s - (s / 3) * 3) - 1;   // dy*34+dx
        const int boff = doff * 256 + (kt & 3) * 64;                 // wave-uniform
#pragma unroll
        for (int c = 0; c < 4; ++c)
            gload16(agp[c] + kt * 64, &Asb[(w * 4 + c) * 512]);
#pragma unroll
        for (int c = 0; c < 4; ++c)
            gload16(bgp[c] + boff, &Bsb[(w * 4 + c) * 512]);
    };

    auto COMPUTE = [&](const _Float16* Asb, const _Float16* Bsb) {
#pragma unroll
        for (int kc = 0; kc < 4; ++kc) {
            const int cx = ((((kc << 1) | kh) ^ (l31 & 7)) << 3);
            half8 af[2], bf[2];
#pragma unroll
            for (int mf = 0; mf < 2; ++mf)
                af[mf] = *(const half8*)&Asb[(wm + mf * 32 + l31) * 64 + cx];
#pragma unroll
            for (int nf = 0; nf < 2; ++nf)
                bf[nf] = *(const half8*)&Bsb[(wn + nf * 32 + l31) * 64 + cx];
#pragma unroll
            for (int mf = 0; mf < 2; ++mf)
#pragma unroll
                for (int nf = 0; nf < 2; ++nf)
                    acc[mf][nf] = MFMA32(af[mf], bf[nf], acc[mf][nf]);
        }
    };

    // prologue: stage kt=0 into buffer 0; single drain+barrier
    STAGE(0, As0, Bs0);
    __syncthreads();

    for (int kt2 = 0; kt2 < ktend; kt2 += 2) {
        // even kt: prefetch kt2+1 into buf1, compute buf0
        STAGE(kt2 + 1, As1, Bs1);
        COMPUTE(As0, Bs0);
        __syncthreads();   // drains prefetch (landed under COMPUTE) + swap
        // odd kt: prefetch kt2+2 into buf0, compute buf1
        if (kt2 + 2 < ktend) STAGE(kt2 + 2, As0, Bs0);
        COMPUTE(As1, Bs1);
        __syncthreads();
    }

#pragma unroll
    for (int mf = 0; mf < 2; ++mf) {
        const int mbase = m0 + wm + mf * 32;   // multiple of 32
        if (!QBLK && mbase >= 512) {
            // V: f16 channel-major [(b*512 + m-512)<<10 + pix]
#pragma unroll
            for (int nf = 0; nf < 2; ++nf) {
                const int pix = p0 + wn + nf * 32 + l31;
#pragma unroll
                for (int reg = 0; reg < 16; ++reg) {
                    const int mv = mbase - 512 + (reg & 3) + 8 * (reg >> 2) + 4 * kh;
                    vb[(((size_t)(b * 512 + mv)) << 10) + pix] =
                        (_Float16)acc[mf][nf][reg];
                }
            }
        } else {
            // headwise: [(b*8+h)<<10 + pix][64], d contiguous in groups of 4
            const int h = mbase >> 6;
            const int dbase = (mbase & 63) + kh * 4;
            _Float16* dst = QBLK ? qt : ktp;
#pragma unroll
            for (int nf = 0; nf < 2; ++nf) {
                const int pix = p0 + wn + nf * 32 + l31;
#pragma unroll
                for (int g = 0; g < 4; ++g) {
                    half4 v4;
#pragma unroll
                    for (int rr = 0; rr < 4; ++rr) {
                        float vv = acc[mf][nf][g * 4 + rr];
                        if (QBLK) vv *= 0.125f;
                        v4[rr] = (_Float16)vv;
                    }
                    *(half4*)&dst[((((size_t)(b * 8 + h)) << 10) + pix) * 64 + dbase + g * 8] = v4;
                }
            }
        }
    }
}

// ---------------------------------------------------------------------------
// Output projection GEMM (16x16x32, tile 128M x 64N, 256 blocks).
// r16/r17: dbuf (As0/As1, Bs0/Bs1; 48KB LDS), STAGE(next)->COMPUTE(cur)->sync.
// ---------------------------------------------------------------------------
template<int M, int K, int KROW>
__global__ __launch_bounds__(256) void out_gemm_kernel(
    const _Float16* __restrict__ A, const _Float16* __restrict__ act,
    float* __restrict__ Cout, const float* __restrict__ bias)
{
    __shared__ _Float16 As0[128 * 64];
    __shared__ _Float16 As1[128 * 64];
    __shared__ _Float16 Bs0[64 * 64];
    __shared__ _Float16 Bs1[64 * 64];
    const int nt = blockIdx.x, mt = blockIdx.y, b = blockIdx.z;
    const int tid = threadIdx.x;
    const int w = tid >> 6, lane = tid & 63;
    const int quad = lane >> 4, l15 = lane & 15;
    const int m0 = mt * 128, p0 = nt * 64;
    const int wm = w * 32;
    const f32x4 Z4 = {0.f, 0.f, 0.f, 0.f};

    const int srow = lane >> 3;
    const int scol = ((lane & 7) ^ srow) * 8;

    const _Float16* agp[4];
#pragma unroll
    for (int c = 0; c < 4; ++c) {
        int row = (w * 4 + c) * 8 + srow;
        agp[c] = A + (size_t)(m0 + row) * K + scol;
    }
    const _Float16* bgp[2];
#pragma unroll
    for (int c = 0; c < 2; ++c) {
        int row = (w * 2 + c) * 8 + srow;
        bgp[c] = act + (size_t)(b * NPIX + p0 + row) * KROW + scol;
    }

    f32x4 acc[2][4];
#pragma unroll
    for (int mi = 0; mi < 2; ++mi)
#pragma unroll
        for (int ni = 0; ni < 4; ++ni) acc[mi][ni] = Z4;

    auto STAGE = [&](int kt, _Float16* Asb, _Float16* Bsb) {
#pragma unroll
        for (int c = 0; c < 4; ++c)
            gload16(agp[c] + kt * 64, &Asb[(w * 4 + c) * 512]);
#pragma unroll
        for (int c = 0; c < 2; ++c)
            gload16(bgp[c] + kt * 64, &Bsb[(w * 2 + c) * 512]);
    };

    auto COMPUTE = [&](const _Float16* Asb, const _Float16* Bsb) {
#pragma unroll
        for (int ks = 0; ks < 2; ++ks) {
            half8 av[2], bv[4];
#pragma unroll
            for (int mi = 0; mi < 2; ++mi) {
                const int rr = wm + mi * 16 + l15;
                av[mi] = *(const half8*)&Asb[rr * 64 + (((ks * 4 + quad) ^ (l15 & 7)) << 3)];
            }
#pragma unroll
            for (int ni = 0; ni < 4; ++ni) {
                const int rr = ni * 16 + l15;
                bv[ni] = *(const half8*)&Bsb[rr * 64 + (((ks * 4 + quad) ^ (l15 & 7)) << 3)];
            }
#pragma unroll
            for (int mi = 0; mi < 2; ++mi)
#pragma unroll
                for (int ni = 0; ni < 4; ++ni)
                    acc[mi][ni] = MFMA16(av[mi], bv[ni], acc[mi][ni]);
        }
    };

    STAGE(0, As0, Bs0);
    __syncthreads();
    for (int kt2 = 0; kt2 < K / 64; kt2 += 2) {
        STAGE(kt2 + 1, As1, Bs1);
        COMPUTE(As0, Bs0);
        __syncthreads();
        if (kt2 + 2 < K / 64) STAGE(kt2 + 2, As0, Bs0);
        COMPUTE(As1, Bs1);
        __syncthreads();
    }

#pragma unroll
    for (int mi = 0; mi < 2; ++mi) {
#pragma unroll
        for (int rr = 0; rr < 4; ++rr) {
            const int m = m0 + wm + mi * 16 + quad * 4 + rr;
            const float bv = bias[m];
#pragma unroll
            for (int ni = 0; ni < 4; ++ni) {
                const int pix = p0 + ni * 16 + l15;
                Cout[(((size_t)(b * M + m)) << 10) + pix] = acc[mi][ni][rr] + bv;
            }
        }
    }
}

// ---------------------------------------------------------------------------
// Attention (r16/r17): K double-buffered (Ks0/Ks1), V retimed into the QK^T
// shadow. Per kt: QKT(K[cur]) -> sync -> issue K(kt+1)->K[other] (flies
// under P-write+PV) -> PV(Vs) -> sync -> issue V(kt+1) (flies under next
// QKT). LDS 80KB -> 2 blocks/CU. Numerics identical to round-6 structure.
// ---------------------------------------------------------------------------
__global__ __launch_bounds__(256) void attn_kernel(
    const _Float16* __restrict__ qt,   // [(b*8+h)<<10 + pix]*64 + d, pre-scaled
    const _Float16* __restrict__ ktp,  // (bh<<16) + pix*64 + d
    const _Float16* __restrict__ vbb,  // [(b*512 + h*64 + d)<<10] + pix
    _Float16* __restrict__ gout)       // [b*1024+pix][512]
{
    __shared__ _Float16 Ks0[128 * 64];   // 16 KB
    __shared__ _Float16 Ks1[128 * 64];   // 16 KB
    __shared__ _Float16 Vs[64 * 128];    // 16 KB
    __shared__ _Float16 Pb[128 * 128];   // 32 KB
    const int qtile = blockIdx.x, bh = blockIdx.y;
    const int b = bh >> 3, h = bh & 7;
    const int p0 = qtile * 128;
    const int tid = threadIdx.x;
    const int w = tid >> 6, lane = tid & 63;
    const int quad = lane >> 4, l15 = lane & 15;
    const f32x4 Z4 = {0.f, 0.f, 0.f, 0.f};

    half8 ones;
#pragma unroll
    for (int u = 0; u < 8; ++u) ones[u] = (_Float16)1.0f;

    half8 qf[2][2];
    {
        const _Float16* qrow =
            qt + ((((size_t)(bh)) << 10) + p0 + w * 32 + l15) * 64;
#pragma unroll
        for (int iff = 0; iff < 2; ++iff)
#pragma unroll
            for (int ks = 0; ks < 2; ++ks)
                qf[iff][ks] = *(const half8*)(qrow + iff * 16 * 64 + ks * 32 + quad * 8);
    }

    const _Float16* kbase = ktp + ((size_t)bh << 16);
    const _Float16* vbase = vbb + (((size_t)(b * 512 + h * 64)) << 10);

    f32x4 oacc[4][2];
#pragma unroll
    for (int mf = 0; mf < 4; ++mf)
#pragma unroll
        for (int iff = 0; iff < 2; ++iff) oacc[mf][iff] = Z4;
    f32x4 racc[2] = {Z4, Z4};

    const int kchunk = (lane & 7) ^ (lane >> 3);

    auto STAGE_K = [&](int kt, _Float16* Kb) {
        const _Float16* kg = kbase + (size_t)(kt * 128) * 64;
#pragma unroll
        for (int i = 0; i < 4; ++i) {
            const int t = i * 4 + w;
            gload16(kg + (t * 8 + (lane >> 3)) * 64 + kchunk * 8, &Kb[t * 512]);
        }
    };
    auto STAGE_V = [&](int kt) {
        const int pk = kt * 128;
#pragma unroll
        for (int i = 0; i < 4; ++i) {
            const int t = i * 4 + w;
            const int vd = t * 4 + (lane >> 4);
            gload16(vbase + ((size_t)vd << 10) + pk + (((lane & 15) ^ (vd & 15)) << 3),
                    &Vs[t * 512]);
        }
    };
    auto QKT = [&](const _Float16* Kb) {
#pragma unroll
        for (int g = 0; g < 2; ++g) {
            f32x4 s[4][2];
#pragma unroll
            for (int jf2 = 0; jf2 < 4; ++jf2) {
                const int jr = (g * 4 + jf2) * 16 + l15;
                const half8 ka0 = *(const half8*)&Kb[jr * 64 + ((quad ^ (l15 & 7)) << 3)];
                const half8 ka1 = *(const half8*)&Kb[jr * 64 + (((4 + quad) ^ (l15 & 7)) << 3)];
#pragma unroll
                for (int iff = 0; iff < 2; ++iff) {
                    s[jf2][iff] = MFMA16(ka0, qf[iff][0], Z4);
                    s[jf2][iff] = MFMA16(ka1, qf[iff][1], s[jf2][iff]);
                }
            }
#pragma unroll
            for (int jf2 = 0; jf2 < 4; ++jf2) {
#pragma unroll
                for (int iff = 0; iff < 2; ++iff) {
                    half4 pv4;
#pragma unroll
                    for (int rr = 0; rr < 4; ++rr)
                        pv4[rr] = (_Float16)__expf(s[jf2][iff][rr] - 8.0f);
                    const int i = w * 32 + iff * 16 + l15;
                    const int c = ((g * 4 + jf2) << 1) + (quad >> 1);
                    *(half4*)&Pb[i * 128 + ((c ^ l15) << 3) + ((quad & 1) << 2)] = pv4;
                }
            }
        }
    };
    auto PV = [&]() {
#pragma unroll
        for (int kc = 0; kc < 4; ++kc) {
            half8 bv[2];
#pragma unroll
            for (int iff = 0; iff < 2; ++iff) {
                const int i = w * 32 + iff * 16 + l15;
                bv[iff] = *(const half8*)&Pb[i * 128 + (((kc * 4 + quad) ^ l15) << 3)];
                racc[iff] = MFMA16(ones, bv[iff], racc[iff]);
            }
#pragma unroll
            for (int mf = 0; mf < 4; ++mf) {
                const int vr = mf * 16 + l15;
                const half8 va = *(const half8*)&Vs[vr * 128 + (((kc * 4 + quad) ^ l15) << 3)];
#pragma unroll
                for (int iff = 0; iff < 2; ++iff)
                    oacc[mf][iff] = MFMA16(va, bv[iff], oacc[mf][iff]);
            }
        }
    };

    // prologue: K0 + V0 staged, drained once
    STAGE_K(0, Ks0);
    STAGE_V(0);
    __syncthreads();

    for (int kt2 = 0; kt2 < 8; kt2 += 2) {
        // even kt = kt2: K in Ks0, V(kt2) in Vs
        QKT(Ks0);
        __syncthreads();               // Ks0 reads done; drains V(kt2) prefetch
        STAGE_K(kt2 + 1, Ks1);         // flies under P-write + PV
        PV();
        __syncthreads();               // Vs reads done; drains K(kt2+1)
        STAGE_V(kt2 + 1);              // flies under next QKT
        // odd kt = kt2+1: K in Ks1
        QKT(Ks1);
        __syncthreads();               // Ks1 reads done; drains V(kt2+1)
        if (kt2 + 2 < 8) STAGE_K(kt2 + 2, Ks0);
        PV();
        __syncthreads();               // Vs reads done; drains K(kt2+2)
        if (kt2 + 2 < 8) STAGE_V(kt2 + 2);
    }

    float rinv[2];
#pragma unroll
    for (int iff = 0; iff < 2; ++iff) rinv[iff] = 1.f / racc[iff][0];

    __syncthreads();
    _Float16* scr = Pb;  // [128 rows][72 halves]
#pragma unroll
    for (int mf = 0; mf < 4; ++mf) {
#pragma unroll
        for (int iff = 0; iff < 2; ++iff) {
            half4 o4;
#pragma unroll
            for (int rr = 0; rr < 4; ++rr)
                o4[rr] = (_Float16)gelu_f(oacc[mf][iff][rr] * rinv[iff]);
            const int i = w * 32 + iff * 16 + l15;
            *(half4*)&scr[i * 72 + mf * 16 + quad * 4] = o4;
        }
    }
    __syncthreads();
    _Float16* go = gout + ((size_t)(b * NPIX + p0)) * INNER + h * 64;
#pragma unroll
    for (int it = 0; it < 4; ++it) {
        const int e = tid + it * 256;
        const int p = e >> 3, dg = e & 7;
        *(half8*)(go + (size_t)p * INNER + dg * 8) = *(const half8*)&scr[p * 72 + dg * 8];
    }
}

// ---------------------------------------------------------------------------
// Workspace (f16 units, ~43.4 MB):
//   xtp 2.37M | Aq 128K | Akv 2.25M | Aout 128K | qt 4M | vb 4M | ktp 4M | gout 4M
// 4 dispatches: prep, qkv (768 flat, balanced XCD swizzle), attn, out.
// ---------------------------------------------------------------------------
extern "C" void kernel_launch(void* const* d_in, const int* in_sizes, int n_in,
                              void* d_out, int out_size, void* d_ws, size_t ws_size,
                              hipStream_t stream)
{
    const float* x    = (const float*)d_in[0];
    const float* Wq   = (const float*)d_in[1];
    const float* Wkv  = (const float*)d_in[2];
    const float* Wout = (const float*)d_in[3];
    const float* bout = (const float*)d_in[4];
    float* out = (float*)d_out;

    _Float16* xtp  = (_Float16*)d_ws;
    _Float16* Aq   = xtp  + (size_t)BATCH * PPIX * DIM;
    _Float16* Akv  = Aq   + (size_t)INNER * DIM;
    _Float16* Aout = Akv  + (size_t)KVCH * 2304;
    _Float16* qt   = Aout + (size_t)DIM * INNER;
    _Float16* vb   = qt   + (size_t)BATCH * NPIX * INNER;
    _Float16* ktp  = vb   + (size_t)BATCH * NPIX * INNER;
    _Float16* gout = ktp  + (size_t)BATCH * NPIX * INNER;

    prep_kernel<<<3616, 256, 0, stream>>>(Wq, Wkv, Wout, x, Aq, Akv, Aout, xtp);
    qkv_gemm_kernel<<<768, 256, 0, stream>>>(Akv, Aq, xtp, qt, ktp, vb);
    attn_kernel<<<dim3(8, 64), 256, 0, stream>>>(qt, ktp, vb, gout);
    out_gemm_kernel<DIM, 512, 512>
        <<<dim3(16, 2, BATCH), 256, 0, stream>>>(Aout, gout, out, bout);
}

// Round 12
// 162.061 us; speedup vs baseline: 2.8483x; 1.0066x over previous
//
#include <hip/hip_runtime.h>
#include <math.h>

// Attention_5471788335537 on gfx950: b=8, dim=256, 32x32, heads=8, dhead=64.
// Round 21: propagate the r20-validated XCD-locality lever (id&7 -> XCD,
// confirmed via r19/r20 FETCH drops) to attn and out:
//  - attn: old grid (8,64) had id&7 = qtile -> every XCD touched all 64 bh
//    (16MB K+V, 4x L2). New flat-512 decode: bh = 8*(id&7) + (r>>3),
//    qtile = r&7 -> one batch per XCD, 8x in-L2 K/V reuse, ~3MB < 4MB L2.
//    Also XCD-aligned with qkv's Q-writer (qt batch x written on XCD x).
//  - out: flat-256 decode b = id&7 -> reads gout on the same XCD attn wrote
//    it (dirty-L2 service of the 8MB act stream); nt = r&15, mt = r>>4.
// Both pure bijective index permutations, balanced per XCD. qkv/prep = r20.
// r20 results: qkv 55.1us, FETCH 15MB (compulsory), MfmaUtil 32%.
// Ledger (dead, do not retry): r10 96KB qkv LDS -> 1 wave/SIMD; r11 B-direct
// -> uncoalesced; r12 cooperative -> capture crash; r15 vmcnt(N)+SB(0) ->
// order-pinning -8us; r18 spin-barrier fusion -> 414us fabric poison;
// dispatch gaps (~70us) unreachable. qkv noise +-5us; absmax AT 0.015625.
#define BATCH 8
#define DIM   256
#define NPIX  1024
#define DHEAD 64
#define INNER 512
#define KVCH  1024
#define PPIX  1156   // 34*34 padded pixels

typedef _Float16 half8 __attribute__((ext_vector_type(8)));
typedef _Float16 half4 __attribute__((ext_vector_type(4)));
typedef float    f32x4 __attribute__((ext_vector_type(4)));
typedef float    f32x16 __attribute__((ext_vector_type(16)));
#define MFMA16(a, b, c) __builtin_amdgcn_mfma_f32_16x16x32_f16(a, b, c, 0, 0, 0)
#define MFMA32(a, b, c) __builtin_amdgcn_mfma_f32_32x32x16_f16(a, b, c, 0, 0, 0)

static __device__ __forceinline__ float gelu_f(float v) {
    return 0.5f * v * (1.0f + erff(v * 0.70710678118654752440f));
}

static __device__ __forceinline__ void gload16(const _Float16* g, _Float16* l) {
    __builtin_amdgcn_global_load_lds(
        (const __attribute__((address_space(1))) unsigned int*)g,
        (__attribute__((address_space(3))) unsigned int*)l, 16, 0, 0);
}

// ---------------------------------------------------------------------------
// Fused prep, r17 block map (3616 blocks):
//   [0,512)      transpose x -> padded xtp interior
//   [512,1024)   Wq -> f16 (coalesced 1:1)
//   [1024,2048)  Wkv reorder via LDS slab (coalesced both sides; stride-9
//                LDS reads, 9 coprime 32 banks -> conflict-free)
//   [2048,2560)  Wout -> f16 (coalesced 1:1)
//   [2560,3616)  zero xtp halo
// ---------------------------------------------------------------------------
__global__ __launch_bounds__(256) void prep_kernel(
    const float* __restrict__ Wq, const float* __restrict__ Wkv,
    const float* __restrict__ Wout, const float* __restrict__ x,
    _Float16* __restrict__ Aq, _Float16* __restrict__ Akv,
    _Float16* __restrict__ Aout, _Float16* __restrict__ xtp)
{
    const int bid = blockIdx.x, tid = threadIdx.x;
    if (bid < 512) {
        __shared__ float ts[64][65];
        const int pt = (bid & 15) * 64, ic0 = ((bid >> 4) & 3) * 64, b = bid >> 6;
        const float* xb = x + (((size_t)(b * DIM + ic0)) << 10) + pt;
#pragma unroll
        for (int e = tid; e < 4096; e += 256) {
            int i = e >> 6, p = e & 63;
            ts[i][p] = xb[((size_t)i << 10) + p];
        }
        __syncthreads();
#pragma unroll
        for (int e = tid; e < 512; e += 256) {
            int p = e >> 3, ig = e & 7;
            int gp = pt + p, y = gp >> 5, xc = gp & 31;
            half8 v;
#pragma unroll
            for (int u = 0; u < 8; ++u) v[u] = (_Float16)ts[ig * 8 + u][p];
            *(half8*)&xtp[((size_t)b * PPIX + (y + 1) * 34 + xc + 1) * 256 + ic0 + ig * 8] = v;
        }
    } else if (bid < 1024) {
        const int e = (bid - 512) * 256 + tid;     // [0,131072) exact
        Aq[e] = (_Float16)Wq[e];
    } else if (bid < 2048) {
        __shared__ float slab[2304];
        const int oc = bid - 1024;
        const float* src = Wkv + (size_t)oc * 2304;
#pragma unroll
        for (int j = tid; j < 2304; j += 256) slab[j] = src[j];
        __syncthreads();
        _Float16* dst = Akv + (size_t)oc * 2304;
#pragma unroll
        for (int j = tid; j < 2304; j += 256) {
            const int ic = j & 255, s = j >> 8;    // j = s*256 + ic
            dst[j] = (_Float16)slab[ic * 9 + s];
        }
    } else if (bid < 2560) {
        const int e = (bid - 2048) * 256 + tid;    // [0,131072) exact
        Aout[e] = (_Float16)Wout[e];
    } else {
        const int he = (bid - 2560) * 256 + tid;   // [0,270336) exact
        int b = he / 33792;                        // 132*256 per batch
        int r = he - b * 33792;
        int hp = r >> 8, ic = r & 255;
        int row, col;
        if (hp < 34)      { row = 0;  col = hp; }
        else if (hp < 68) { row = 33; col = hp - 34; }
        else { int k2 = hp - 68; row = 1 + (k2 >> 1); col = (k2 & 1) * 33; }
        xtp[((size_t)b * PPIX + row * 34 + col) * 256 + ic] = (_Float16)0.f;
    }
}

// ---------------------------------------------------------------------------
// Fused q + kv implicit GEMM, 32x32x16 MFMA, tile 128x128, waves 2x2.
// r20: 1-D grid 768, balanced XCD-locality decode (id&7 -> XCD, measured):
//   x = id&7, r = id>>3 (96 units/XCD, 2432 kt/XCD uniform)
//   r<64 (KV): nt=r&7, mtl=2*(x&3)+((r>>3)&1), b=4*(x>>2)+(r>>4)
//   r>=64 (Q): qidx=r-64, nt=qidx&7, qmt=qidx>>3, b=x
// KV mtl<4 -> K headwise, 4..7 -> V channel-major; Q (4 kts) q*0.125 -> qt.
// r14 schedule (best): dbuf, pairwise kt unroll, STAGE(next)->COMPUTE(cur)
// ->__syncthreads. XOR-chunk staging swizzle; frag reads conflict-free.
// ---------------------------------------------------------------------------
__global__ __launch_bounds__(256) void qkv_gemm_kernel(
    const _Float16* __restrict__ Akv, const _Float16* __restrict__ Aq,
    const _Float16* __restrict__ xtp, _Float16* __restrict__ qt,
    _Float16* __restrict__ ktp, _Float16* __restrict__ vb)
{
    __shared__ _Float16 As0[128 * 64];   // 16 KB
    __shared__ _Float16 As1[128 * 64];   // 16 KB
    __shared__ _Float16 Bs0[128 * 64];   // 16 KB
    __shared__ _Float16 Bs1[128 * 64];   // 16 KB
    const int id = blockIdx.x;
    const int x = id & 7, r = id >> 3;               // x = XCD slot, r in [0,96)
    int mtl, nt, b;
    bool QBLK;
    if (r < 64) {                                    // KV: 64 units/XCD
        QBLK = false;
        nt  = r & 7;
        mtl = 2 * (x & 3) + ((r >> 3) & 1);          // [0,8)
        b   = 4 * (x >> 2) + (r >> 4);               // [0,8)
    } else {                                         // Q: 32 units/XCD
        QBLK = true;
        const int qidx = r - 64;
        nt  = qidx & 7;
        mtl = qidx >> 3;                             // [0,4)
        b   = x;                                     // b = x (in x's batch quad)
    }
    const int tid = threadIdx.x;
    const int w = tid >> 6, lane = tid & 63;
    const int l31 = lane & 31, kh = lane >> 5;
    const int m0 = mtl * 128, p0 = nt * 128;
    const int wm = (w >> 1) * 64, wn = (w & 1) * 64;

    const int srow = lane >> 3;
    const int scol = ((lane & 7) ^ srow) * 8;

    const _Float16* abase = QBLK ? Aq : Akv;
    const int astride = QBLK ? 256 : 2304;
    const int ktend = QBLK ? 4 : 36;   // both even (pairwise unroll relies on it)

    const _Float16* agp[4];
    const _Float16* bgp[4];
#pragma unroll
    for (int c = 0; c < 4; ++c) {
        int row = (w * 4 + c) * 8 + srow;
        agp[c] = abase + (size_t)(m0 + row) * astride + scol;
        int p = p0 + row, py = p >> 5, px = p & 31;
        bgp[c] = xtp + ((size_t)b * PPIX + (py + 1) * 34 + px + 1) * 256 + scol;
    }

    f32x16 acc[2][2];
#pragma unroll
    for (int mf = 0; mf < 2; ++mf)
#pragma unroll
        for (int nf = 0; nf < 2; ++nf)
#pragma unroll
            for (int rr = 0; rr < 16; ++rr) acc[mf][nf][rr] = 0.f;

    auto STAGE = [&](int kt, _Float16* Asb, _Float16* Bsb) {
        const int s = QBLK ? 4 : (kt >> 2);
        const int doff = (s / 3 - 1) * 34 + (s - (s / 3) * 3) - 1;   // dy*34+dx
        const int boff = doff * 256 + (kt & 3) * 64;                 // wave-uniform
#pragma unroll
        for (int c = 0; c < 4; ++c)
            gload16(agp[c] + kt * 64, &Asb[(w * 4 + c) * 512]);
#pragma unroll
        for (int c = 0; c < 4; ++c)
            gload16(bgp[c] + boff, &Bsb[(w * 4 + c) * 512]);
    };

    auto COMPUTE = [&](const _Float16* Asb, const _Float16* Bsb) {
#pragma unroll
        for (int kc = 0; kc < 4; ++kc) {
            const int cx = ((((kc << 1) | kh) ^ (l31 & 7)) << 3);
            half8 af[2], bf[2];
#pragma unroll
            for (int mf = 0; mf < 2; ++mf)
                af[mf] = *(const half8*)&Asb[(wm + mf * 32 + l31) * 64 + cx];
#pragma unroll
            for (int nf = 0; nf < 2; ++nf)
                bf[nf] = *(const half8*)&Bsb[(wn + nf * 32 + l31) * 64 + cx];
#pragma unroll
            for (int mf = 0; mf < 2; ++mf)
#pragma unroll
                for (int nf = 0; nf < 2; ++nf)
                    acc[mf][nf] = MFMA32(af[mf], bf[nf], acc[mf][nf]);
        }
    };

    // prologue: stage kt=0 into buffer 0; single drain+barrier
    STAGE(0, As0, Bs0);
    __syncthreads();

    for (int kt2 = 0; kt2 < ktend; kt2 += 2) {
        // even kt: prefetch kt2+1 into buf1, compute buf0
        STAGE(kt2 + 1, As1, Bs1);
        COMPUTE(As0, Bs0);
        __syncthreads();   // drains prefetch (landed under COMPUTE) + swap
        // odd kt: prefetch kt2+2 into buf0, compute buf1
        if (kt2 + 2 < ktend) STAGE(kt2 + 2, As0, Bs0);
        COMPUTE(As1, Bs1);
        __syncthreads();
    }

#pragma unroll
    for (int mf = 0; mf < 2; ++mf) {
        const int mbase = m0 + wm + mf * 32;   // multiple of 32
        if (!QBLK && mbase >= 512) {
            // V: f16 channel-major [(b*512 + m-512)<<10 + pix]
#pragma unroll
            for (int nf = 0; nf < 2; ++nf) {
                const int pix = p0 + wn + nf * 32 + l31;
#pragma unroll
                for (int reg = 0; reg < 16; ++reg) {
                    const int mv = mbase - 512 + (reg & 3) + 8 * (reg >> 2) + 4 * kh;
                    vb[(((size_t)(b * 512 + mv)) << 10) + pix] =
                        (_Float16)acc[mf][nf][reg];
                }
            }
        } else {
            // headwise: [(b*8+h)<<10 + pix][64], d contiguous in groups of 4
            const int h = mbase >> 6;
            const int dbase = (mbase & 63) + kh * 4;
            _Float16* dst = QBLK ? qt : ktp;
#pragma unroll
            for (int nf = 0; nf < 2; ++nf) {
                const int pix = p0 + wn + nf * 32 + l31;
#pragma unroll
                for (int g = 0; g < 4; ++g) {
                    half4 v4;
#pragma unroll
                    for (int rr = 0; rr < 4; ++rr) {
                        float vv = acc[mf][nf][g * 4 + rr];
                        if (QBLK) vv *= 0.125f;
                        v4[rr] = (_Float16)vv;
                    }
                    *(half4*)&dst[((((size_t)(b * 8 + h)) << 10) + pix) * 64 + dbase + g * 8] = v4;
                }
            }
        }
    }
}

// ---------------------------------------------------------------------------
// Output projection GEMM (16x16x32, tile 128M x 64N, flat 256 blocks).
// Round 21: XCD decode b = id&7 -> act (gout) read on the same XCD where
// attn's batch-b blocks wrote it (dirty-L2 service); nt = r&15, mt = r>>4.
// r16/r17 dbuf schedule: STAGE(next)->COMPUTE(cur)->sync.
// ---------------------------------------------------------------------------
template<int M, int K, int KROW>
__global__ __launch_bounds__(256) void out_gemm_kernel(
    const _Float16* __restrict__ A, const _Float16* __restrict__ act,
    float* __restrict__ Cout, const float* __restrict__ bias)
{
    __shared__ _Float16 As0[128 * 64];
    __shared__ _Float16 As1[128 * 64];
    __shared__ _Float16 Bs0[64 * 64];
    __shared__ _Float16 Bs1[64 * 64];
    const int id = blockIdx.x;
    const int b = id & 7, r = id >> 3;     // 32 units/XCD-slot
    const int nt = r & 15, mt = r >> 4;    // [0,16) x [0,2)
    const int tid = threadIdx.x;
    const int w = tid >> 6, lane = tid & 63;
    const int quad = lane >> 4, l15 = lane & 15;
    const int m0 = mt * 128, p0 = nt * 64;
    const int wm = w * 32;
    const f32x4 Z4 = {0.f, 0.f, 0.f, 0.f};

    const int srow = lane >> 3;
    const int scol = ((lane & 7) ^ srow) * 8;

    const _Float16* agp[4];
#pragma unroll
    for (int c = 0; c < 4; ++c) {
        int row = (w * 4 + c) * 8 + srow;
        agp[c] = A + (size_t)(m0 + row) * K + scol;
    }
    const _Float16* bgp[2];
#pragma unroll
    for (int c = 0; c < 2; ++c) {
        int row = (w * 2 + c) * 8 + srow;
        bgp[c] = act + (size_t)(b * NPIX + p0 + row) * KROW + scol;
    }

    f32x4 acc[2][4];
#pragma unroll
    for (int mi = 0; mi < 2; ++mi)
#pragma unroll
        for (int ni = 0; ni < 4; ++ni) acc[mi][ni] = Z4;

    auto STAGE = [&](int kt, _Float16* Asb, _Float16* Bsb) {
#pragma unroll
        for (int c = 0; c < 4; ++c)
            gload16(agp[c] + kt * 64, &Asb[(w * 4 + c) * 512]);
#pragma unroll
        for (int c = 0; c < 2; ++c)
            gload16(bgp[c] + kt * 64, &Bsb[(w * 2 + c) * 512]);
    };

    auto COMPUTE = [&](const _Float16* Asb, const _Float16* Bsb) {
#pragma unroll
        for (int ks = 0; ks < 2; ++ks) {
            half8 av[2], bv[4];
#pragma unroll
            for (int mi = 0; mi < 2; ++mi) {
                const int rr = wm + mi * 16 + l15;
                av[mi] = *(const half8*)&Asb[rr * 64 + (((ks * 4 + quad) ^ (l15 & 7)) << 3)];
            }
#pragma unroll
            for (int ni = 0; ni < 4; ++ni) {
                const int rr = ni * 16 + l15;
                bv[ni] = *(const half8*)&Bsb[rr * 64 + (((ks * 4 + quad) ^ (l15 & 7)) << 3)];
            }
#pragma unroll
            for (int mi = 0; mi < 2; ++mi)
#pragma unroll
                for (int ni = 0; ni < 4; ++ni)
                    acc[mi][ni] = MFMA16(av[mi], bv[ni], acc[mi][ni]);
        }
    };

    STAGE(0, As0, Bs0);
    __syncthreads();
    for (int kt2 = 0; kt2 < K / 64; kt2 += 2) {
        STAGE(kt2 + 1, As1, Bs1);
        COMPUTE(As0, Bs0);
        __syncthreads();
        if (kt2 + 2 < K / 64) STAGE(kt2 + 2, As0, Bs0);
        COMPUTE(As1, Bs1);
        __syncthreads();
    }

#pragma unroll
    for (int mi = 0; mi < 2; ++mi) {
#pragma unroll
        for (int rr = 0; rr < 4; ++rr) {
            const int m = m0 + wm + mi * 16 + quad * 4 + rr;
            const float bv = bias[m];
#pragma unroll
            for (int ni = 0; ni < 4; ++ni) {
                const int pix = p0 + ni * 16 + l15;
                Cout[(((size_t)(b * M + m)) << 10) + pix] = acc[mi][ni][rr] + bv;
            }
        }
    }
}

// ---------------------------------------------------------------------------
// Attention (r16/r17 pipeline): K double-buffered (Ks0/Ks1), V retimed into
// the QK^T shadow. Round 21: flat 512 grid, XCD decode — bh = 8*(id&7) +
// (r>>3), qtile = r&7: one batch per XCD, all 8 qtiles of each bh on one
// XCD (8x in-L2 K/V reuse, ~3MB < 4MB L2); XCD-aligned with qkv's qt writer.
// LDS 80KB -> 2 blocks/CU. Numerics identical to round-6 structure.
// ---------------------------------------------------------------------------
__global__ __launch_bounds__(256) void attn_kernel(
    const _Float16* __restrict__ qt,   // [(b*8+h)<<10 + pix]*64 + d, pre-scaled
    const _Float16* __restrict__ ktp,  // (bh<<16) + pix*64 + d
    const _Float16* __restrict__ vbb,  // [(b*512 + h*64 + d)<<10] + pix
    _Float16* __restrict__ gout)       // [b*1024+pix][512]
{
    __shared__ _Float16 Ks0[128 * 64];   // 16 KB
    __shared__ _Float16 Ks1[128 * 64];   // 16 KB
    __shared__ _Float16 Vs[64 * 128];    // 16 KB
    __shared__ _Float16 Pb[128 * 128];   // 32 KB
    const int id = blockIdx.x;
    const int xs = id & 7, r = id >> 3;          // 64 units/XCD-slot
    const int qtile = r & 7;
    const int bh = xs * 8 + (r >> 3);            // one batch per XCD slot
    const int b = bh >> 3, h = bh & 7;
    const int p0 = qtile * 128;
    const int tid = threadIdx.x;
    const int w = tid >> 6, lane = tid & 63;
    const int quad = lane >> 4, l15 = lane & 15;
    const f32x4 Z4 = {0.f, 0.f, 0.f, 0.f};

    half8 ones;
#pragma unroll
    for (int u = 0; u < 8; ++u) ones[u] = (_Float16)1.0f;

    half8 qf[2][2];
    {
        const _Float16* qrow =
            qt + ((((size_t)(bh)) << 10) + p0 + w * 32 + l15) * 64;
#pragma unroll
        for (int iff = 0; iff < 2; ++iff)
#pragma unroll
            for (int ks = 0; ks < 2; ++ks)
                qf[iff][ks] = *(const half8*)(qrow + iff * 16 * 64 + ks * 32 + quad * 8);
    }

    const _Float16* kbase = ktp + ((size_t)bh << 16);
    const _Float16* vbase = vbb + (((size_t)(b * 512 + h * 64)) << 10);

    f32x4 oacc[4][2];
#pragma unroll
    for (int mf = 0; mf < 4; ++mf)
#pragma unroll
        for (int iff = 0; iff < 2; ++iff) oacc[mf][iff] = Z4;
    f32x4 racc[2] = {Z4, Z4};

    const int kchunk = (lane & 7) ^ (lane >> 3);

    auto STAGE_K = [&](int kt, _Float16* Kb) {
        const _Float16* kg = kbase + (size_t)(kt * 128) * 64;
#pragma unroll
        for (int i = 0; i < 4; ++i) {
            const int t = i * 4 + w;
            gload16(kg + (t * 8 + (lane >> 3)) * 64 + kchunk * 8, &Kb[t * 512]);
        }
    };
    auto STAGE_V = [&](int kt) {
        const int pk = kt * 128;
#pragma unroll
        for (int i = 0; i < 4; ++i) {
            const int t = i * 4 + w;
            const int vd = t * 4 + (lane >> 4);
            gload16(vbase + ((size_t)vd << 10) + pk + (((lane & 15) ^ (vd & 15)) << 3),
                    &Vs[t * 512]);
        }
    };
    auto QKT = [&](const _Float16* Kb) {
#pragma unroll
        for (int g = 0; g < 2; ++g) {
            f32x4 s[4][2];
#pragma unroll
            for (int jf2 = 0; jf2 < 4; ++jf2) {
                const int jr = (g * 4 + jf2) * 16 + l15;
                const half8 ka0 = *(const half8*)&Kb[jr * 64 + ((quad ^ (l15 & 7)) << 3)];
                const half8 ka1 = *(const half8*)&Kb[jr * 64 + (((4 + quad) ^ (l15 & 7)) << 3)];
#pragma unroll
                for (int iff = 0; iff < 2; ++iff) {
                    s[jf2][iff] = MFMA16(ka0, qf[iff][0], Z4);
                    s[jf2][iff] = MFMA16(ka1, qf[iff][1], s[jf2][iff]);
                }
            }
#pragma unroll
            for (int jf2 = 0; jf2 < 4; ++jf2) {
#pragma unroll
                for (int iff = 0; iff < 2; ++iff) {
                    half4 pv4;
#pragma unroll
                    for (int rr = 0; rr < 4; ++rr)
                        pv4[rr] = (_Float16)__expf(s[jf2][iff][rr] - 8.0f);
                    const int i = w * 32 + iff * 16 + l15;
                    const int c = ((g * 4 + jf2) << 1) + (quad >> 1);
                    *(half4*)&Pb[i * 128 + ((c ^ l15) << 3) + ((quad & 1) << 2)] = pv4;
                }
            }
        }
    };
    auto PV = [&]() {
#pragma unroll
        for (int kc = 0; kc < 4; ++kc) {
            half8 bv[2];
#pragma unroll
            for (int iff = 0; iff < 2; ++iff) {
                const int i = w * 32 + iff * 16 + l15;
                bv[iff] = *(const half8*)&Pb[i * 128 + (((kc * 4 + quad) ^ l15) << 3)];
                racc[iff] = MFMA16(ones, bv[iff], racc[iff]);
            }
#pragma unroll
            for (int mf = 0; mf < 4; ++mf) {
                const int vr = mf * 16 + l15;
                const half8 va = *(const half8*)&Vs[vr * 128 + (((kc * 4 + quad) ^ l15) << 3)];
#pragma unroll
                for (int iff = 0; iff < 2; ++iff)
                    oacc[mf][iff] = MFMA16(va, bv[iff], oacc[mf][iff]);
            }
        }
    };

    // prologue: K0 + V0 staged, drained once
    STAGE_K(0, Ks0);
    STAGE_V(0);
    __syncthreads();

    for (int kt2 = 0; kt2 < 8; kt2 += 2) {
        // even kt = kt2: K in Ks0, V(kt2) in Vs
        QKT(Ks0);
        __syncthreads();               // Ks0 reads done; drains V(kt2) prefetch
        STAGE_K(kt2 + 1, Ks1);         // flies under P-write + PV
        PV();
        __syncthreads();               // Vs reads done; drains K(kt2+1)
        STAGE_V(kt2 + 1);              // flies under next QKT
        // odd kt = kt2+1: K in Ks1
        QKT(Ks1);
        __syncthreads();               // Ks1 reads done; drains V(kt2+1)
        if (kt2 + 2 < 8) STAGE_K(kt2 + 2, Ks0);
        PV();
        __syncthreads();               // Vs reads done; drains K(kt2+2)
        if (kt2 + 2 < 8) STAGE_V(kt2 + 2);
    }

    float rinv[2];
#pragma unroll
    for (int iff = 0; iff < 2; ++iff) rinv[iff] = 1.f / racc[iff][0];

    __syncthreads();
    _Float16* scr = Pb;  // [128 rows][72 halves]
#pragma unroll
    for (int mf = 0; mf < 4; ++mf) {
#pragma unroll
        for (int iff = 0; iff < 2; ++iff) {
            half4 o4;
#pragma unroll
            for (int rr = 0; rr < 4; ++rr)
                o4[rr] = (_Float16)gelu_f(oacc[mf][iff][rr] * rinv[iff]);
            const int i = w * 32 + iff * 16 + l15;
            *(half4*)&scr[i * 72 + mf * 16 + quad * 4] = o4;
        }
    }
    __syncthreads();
    _Float16* go = gout + ((size_t)(b * NPIX + p0)) * INNER + h * 64;
#pragma unroll
    for (int it = 0; it < 4; ++it) {
        const int e = tid + it * 256;
        const int p = e >> 3, dg = e & 7;
        *(half8*)(go + (size_t)p * INNER + dg * 8) = *(const half8*)&scr[p * 72 + dg * 8];
    }
}

// ---------------------------------------------------------------------------
// Workspace (f16 units, ~43.4 MB):
//   xtp 2.37M | Aq 128K | Akv 2.25M | Aout 128K | qt 4M | vb 4M | ktp 4M | gout 4M
// 4 dispatches: prep, qkv (768 flat), attn (512 flat), out (256 flat) —
// all MFMA kernels XCD-swizzled.
// ---------------------------------------------------------------------------
extern "C" void kernel_launch(void* const* d_in, const int* in_sizes, int n_in,
                              void* d_out, int out_size, void* d_ws, size_t ws_size,
                              hipStream_t stream)
{
    const float* x    = (const float*)d_in[0];
    const float* Wq   = (const float*)d_in[1];
    const float* Wkv  = (const float*)d_in[2];
    const float* Wout = (const float*)d_in[3];
    const float* bout = (const float*)d_in[4];
    float* out = (float*)d_out;

    _Float16* xtp  = (_Float16*)d_ws;
    _Float16* Aq   = xtp  + (size_t)BATCH * PPIX * DIM;
    _Float16* Akv  = Aq   + (size_t)INNER * DIM;
    _Float16* Aout = Akv  + (size_t)KVCH * 2304;
    _Float16* qt   = Aout + (size_t)DIM * INNER;
    _Float16* vb   = qt   + (size_t)BATCH * NPIX * INNER;
    _Float16* ktp  = vb   + (size_t)BATCH * NPIX * INNER;
    _Float16* gout = ktp  + (size_t)BATCH * NPIX * INNER;

    prep_kernel<<<3616, 256, 0, stream>>>(Wq, Wkv, Wout, x, Aq, Akv, Aout, xtp);
    qkv_gemm_kernel<<<768, 256, 0, stream>>>(Akv, Aq, xtp, qt, ktp, vb);
    attn_kernel<<<512, 256, 0, stream>>>(qt, ktp, vb, gout);
    out_gemm_kernel<DIM, 512, 512>
        <<<256, 256, 0, stream>>>(Aout, gout, out, bout);
}